// Round 1
// baseline (634.152 us; speedup 1.0000x reference)
//
#include <hip/hip_runtime.h>
#include <math.h>

#define NEG_SLOPE 0.2f

static __device__ __forceinline__ float leaky(float x) { return x >= 0.f ? x : NEG_SLOPE * x; }

// ---------------- CSR build ----------------

__global__ void hist_kernel(const int* __restrict__ dst, int* __restrict__ counts, int E, int Nn) {
    int i = blockIdx.x * blockDim.x + threadIdx.x;
    int tot = E + Nn;
    if (i < tot) {
        int d = (i < E) ? dst[i] : (i - E);   // self-loop for i >= E
        atomicAdd(&counts[d], 1);
    }
}

// block of 256 threads scans 1024 counts; writes per-element exclusive-within-block
// prefix and the block total.
__global__ void scan1_kernel(const int* __restrict__ counts, int* __restrict__ partial,
                             int* __restrict__ blockSums, int Nn) {
    __shared__ int sh[1024];
    int b = blockIdx.x, t = threadIdx.x;
    int base = b * 1024;
    int orig[4];
    for (int r = 0; r < 4; r++) {
        int i = t + r * 256;
        int v = (base + i < Nn) ? counts[base + i] : 0;
        orig[r] = v;
        sh[i] = v;
    }
    __syncthreads();
    for (int off = 1; off < 1024; off <<= 1) {
        int vals[4];
        for (int r = 0; r < 4; r++) { int i = t + r * 256; vals[r] = (i >= off) ? sh[i - off] : 0; }
        __syncthreads();
        for (int r = 0; r < 4; r++) { int i = t + r * 256; sh[i] += vals[r]; }
        __syncthreads();
    }
    for (int r = 0; r < 4; r++) {
        int i = t + r * 256;
        if (base + i < Nn) partial[base + i] = sh[i] - orig[r];
    }
    if (t == 0) blockSums[b] = sh[1023];
}

__global__ void scan2_kernel(int* __restrict__ blockSums, int nb) {
    if (threadIdx.x == 0 && blockIdx.x == 0) {
        int s = 0;
        for (int i = 0; i < nb; i++) { int v = blockSums[i]; blockSums[i] = s; s += v; }
    }
}

__global__ void finalize_kernel(const int* __restrict__ partial, const int* __restrict__ blockOff,
                                int* __restrict__ row_ptr, int Nn, int Etot) {
    int i = blockIdx.x * blockDim.x + threadIdx.x;
    if (i < Nn) row_ptr[i] = partial[i] + blockOff[i >> 10];
    if (i == 0) row_ptr[Nn] = Etot;
}

__global__ void scatter_kernel(const int* __restrict__ srcE, const int* __restrict__ dstE,
                               const int* __restrict__ row_ptr, int* __restrict__ fill,
                               int* __restrict__ srcs, int E, int Nn) {
    int i = blockIdx.x * blockDim.x + threadIdx.x;
    int tot = E + Nn;
    if (i < tot) {
        int s, d;
        if (i < E) { s = srcE[i]; d = dstE[i]; }
        else       { s = d = i - E; }
        int pos = row_ptr[d] + atomicAdd(&fill[d], 1);
        srcs[pos] = s;
    }
}

// ---------------- fp32 GEMM: C[M,256] = A[M,256] @ B[256,256] ----------------
// 64x64 block tile, BK=16, 256 threads, 4x4 microtile per thread.
__global__ __launch_bounds__(256) void gemm_kernel(const float* __restrict__ A,
                                                   const float* __restrict__ B,
                                                   float* __restrict__ C, int M) {
    __shared__ float As[16][64];       // As[k][m] (transposed on store)
    __shared__ float Bs[16][68];       // Bs[k][n], padded: 68*4B = 272B, 16B aligned

    int bm = blockIdx.x * 64;
    int bn = blockIdx.y * 64;
    int tid = threadIdx.x;
    int tx = tid & 15;       // n-group
    int ty = tid >> 4;       // m-group

    float acc[4][4] = {};

    for (int k0 = 0; k0 < 256; k0 += 16) {
        // load A tile (64 rows x 16 k), transposed into As
        int ar = tid >> 2;
        int kq = (tid & 3) << 2;
        int arow = bm + ar;
        const float* ap = A + (size_t)(arow < M ? arow : (M - 1)) * 256 + k0 + kq;
        float4 av = *(const float4*)ap;
        if (arow >= M) { av.x = 0.f; av.y = 0.f; av.z = 0.f; av.w = 0.f; }
        As[kq + 0][ar] = av.x;
        As[kq + 1][ar] = av.y;
        As[kq + 2][ar] = av.z;
        As[kq + 3][ar] = av.w;
        // load B tile (16 k x 64 n)
        int bk = tid >> 4;
        int bn4 = (tid & 15) << 2;
        float4 bv = *(const float4*)(B + (size_t)(k0 + bk) * 256 + bn + bn4);
        *(float4*)&Bs[bk][bn4] = bv;
        __syncthreads();

#pragma unroll
        for (int kk = 0; kk < 16; kk++) {
            float4 a = *(const float4*)&As[kk][ty << 2];
            float4 b = *(const float4*)&Bs[kk][tx << 2];
            float aa[4] = { a.x, a.y, a.z, a.w };
            float bb[4] = { b.x, b.y, b.z, b.w };
#pragma unroll
            for (int i = 0; i < 4; i++)
#pragma unroll
                for (int j = 0; j < 4; j++)
                    acc[i][j] = fmaf(aa[i], bb[j], acc[i][j]);
        }
        __syncthreads();
    }

#pragma unroll
    for (int i = 0; i < 4; i++) {
        int row = bm + (ty << 2) + i;
        if (row < M) {
            float4 v; v.x = acc[i][0]; v.y = acc[i][1]; v.z = acc[i][2]; v.w = acc[i][3];
            *(float4*)(C + (size_t)row * 256 + bn + (tx << 2)) = v;
        }
    }
}

// ---------------- attention coefficients ----------------
// block = 256 threads = one node; wave w (64 lanes) = head w.
__global__ __launch_bounds__(256) void attn_kernel(const float* __restrict__ G,
                                                   const float* __restrict__ att_s,
                                                   const float* __restrict__ att_d,
                                                   float* __restrict__ a_src,
                                                   float* __restrict__ a_dst) {
    int n = blockIdx.x;
    int t = threadIdx.x;
    float g = G[(size_t)n * 256 + t];
    float ps = g * att_s[t];
    float pd = g * att_d[t];
#pragma unroll
    for (int off = 32; off; off >>= 1) {
        ps += __shfl_xor(ps, off);
        pd += __shfl_xor(pd, off);
    }
    if ((t & 63) == 0) {
        int head = t >> 6;
        a_src[n * 4 + head] = ps;
        a_dst[n * 4 + head] = pd;
    }
}

// ---------------- edge softmax + aggregation ----------------
// block = 256 threads = one dst node. thread t = (head = t>>6, col = t&63).
__global__ __launch_bounds__(256) void agg_kernel(const float* __restrict__ G,
                                                  const float* __restrict__ a_src,
                                                  const float* __restrict__ a_dst,
                                                  const int* __restrict__ row_ptr,
                                                  const int* __restrict__ srcs,
                                                  const float* __restrict__ bias,
                                                  float* __restrict__ out, int do_relu) {
    int n = blockIdx.x;
    int t = threadIdx.x;
    int head = t >> 6;
    int lane = t & 63;

    int start = row_ptr[n];
    int end = row_ptr[n + 1];

    float adn = a_dst[n * 4 + head];

    // pass 1: per-head max over incoming edges
    float m = -1e30f;
    for (int e = start + lane; e < end; e += 64) {
        int s = srcs[e];
        float al = leaky(a_src[s * 4 + head] + adn);
        m = fmaxf(m, al);
    }
#pragma unroll
    for (int off = 32; off; off >>= 1) m = fmaxf(m, __shfl_xor(m, off));

    __shared__ float e_lds[64][5];   // [lane][head], padded
    __shared__ int s_lds[64];

    float denom = 0.f;
    float acc = 0.f;

    for (int c0 = start; c0 < end; c0 += 64) {
        int cnt = min(64, end - c0);
        float ev = 0.f;
        if (lane < cnt) {
            int s = srcs[c0 + lane];
            if (head == 0) s_lds[lane] = s;
            float al = leaky(a_src[s * 4 + head] + adn);
            ev = expf(al - m);
        }
        e_lds[lane][head] = ev;
        denom += ev;
        __syncthreads();
#pragma unroll 4
        for (int j = 0; j < cnt; j++) {
            float wgt = e_lds[j][head];
            int s = s_lds[j];
            acc += wgt * G[(size_t)s * 256 + t];
        }
        __syncthreads();
    }

#pragma unroll
    for (int off = 32; off; off >>= 1) denom += __shfl_xor(denom, off);

    float r = acc / denom + bias[t];
    if (do_relu) r = fmaxf(r, 0.f);
    out[(size_t)n * 256 + t] = r;
}

// ---------------- launch ----------------

extern "C" void kernel_launch(void* const* d_in, const int* in_sizes, int n_in,
                              void* d_out, int out_size, void* d_ws, size_t ws_size,
                              hipStream_t stream) {
    const float* x   = (const float*)d_in[0];
    const int*   ei  = (const int*)d_in[1];
    const float* W1  = (const float*)d_in[2];
    const float* as1 = (const float*)d_in[3];
    const float* ad1 = (const float*)d_in[4];
    const float* b1  = (const float*)d_in[5];
    const float* W2  = (const float*)d_in[6];
    const float* as2 = (const float*)d_in[7];
    const float* ad2 = (const float*)d_in[8];
    const float* b2  = (const float*)d_in[9];

    int N = in_sizes[0] / 256;
    int E = in_sizes[1] / 2;
    int Etot = E + N;
    const int* srcE = ei;
    const int* dstE = ei + E;
    float* out = (float*)d_out;

    char* w = (char*)d_ws;
    auto alloc = [&](size_t bytes) -> char* {
        char* p = w;
        w += (bytes + 255) & ~(size_t)255;
        return p;
    };
    float* G       = (float*)alloc((size_t)N * 256 * 4);
    float* a_src   = (float*)alloc((size_t)N * 4 * 4);
    float* a_dst   = (float*)alloc((size_t)N * 4 * 4);
    int* counts    = (int*)alloc((size_t)N * 4);
    int* partial   = (int*)alloc((size_t)N * 4);
    int* fill      = (int*)alloc((size_t)N * 4);
    int* row_ptr   = (int*)alloc(((size_t)N + 1) * 4);
    int* srcs      = (int*)alloc((size_t)Etot * 4);
    int* blockSums = (int*)alloc(256 * 4);

    hipMemsetAsync(counts, 0, (size_t)N * 4, stream);
    hipMemsetAsync(fill, 0, (size_t)N * 4, stream);

    int tot = Etot;
    hist_kernel<<<(tot + 255) / 256, 256, 0, stream>>>(dstE, counts, E, N);
    int nScanBlocks = (N + 1023) / 1024;
    scan1_kernel<<<nScanBlocks, 256, 0, stream>>>(counts, partial, blockSums, N);
    scan2_kernel<<<1, 64, 0, stream>>>(blockSums, nScanBlocks);
    finalize_kernel<<<(N + 255) / 256, 256, 0, stream>>>(partial, blockSums, row_ptr, N, Etot);
    scatter_kernel<<<(tot + 255) / 256, 256, 0, stream>>>(srcE, dstE, row_ptr, fill, srcs, E, N);

    dim3 ggrid((N + 63) / 64, 4);

    // layer 1: G = x @ W1 ; a_src/a_dst ; aggregate -> d_out (relu)
    gemm_kernel<<<ggrid, 256, 0, stream>>>(x, W1, G, N);
    attn_kernel<<<N, 256, 0, stream>>>(G, as1, ad1, a_src, a_dst);
    agg_kernel<<<N, 256, 0, stream>>>(G, a_src, a_dst, row_ptr, srcs, b1, out, 1);

    // layer 2: G = h1 @ W2 ; a_src/a_dst ; aggregate -> d_out (no relu)
    gemm_kernel<<<ggrid, 256, 0, stream>>>(out, W2, G, N);
    attn_kernel<<<N, 256, 0, stream>>>(G, as2, ad2, a_src, a_dst);
    agg_kernel<<<N, 256, 0, stream>>>(G, a_src, a_dst, row_ptr, srcs, b2, out, 0);
}

// Round 2
// 497.819 us; speedup vs baseline: 1.2739x; 1.2739x over previous
//
#include <hip/hip_runtime.h>
#include <math.h>

#define NEG_SLOPE 0.2f

typedef __attribute__((ext_vector_type(8))) short bf16x8;
typedef __attribute__((ext_vector_type(4))) float f32x4;
typedef __attribute__((ext_vector_type(4))) unsigned short u16x4;

static __device__ __forceinline__ f32x4 lky4(f32x4 v) {
    f32x4 r;
    r.x = v.x >= 0.f ? v.x : NEG_SLOPE * v.x;
    r.y = v.y >= 0.f ? v.y : NEG_SLOPE * v.y;
    r.z = v.z >= 0.f ? v.z : NEG_SLOPE * v.z;
    r.w = v.w >= 0.f ? v.w : NEG_SLOPE * v.w;
    return r;
}
static __device__ __forceinline__ f32x4 max4(f32x4 a, f32x4 b) {
    f32x4 r;
    r.x = fmaxf(a.x, b.x); r.y = fmaxf(a.y, b.y);
    r.z = fmaxf(a.z, b.z); r.w = fmaxf(a.w, b.w);
    return r;
}
static __device__ __forceinline__ f32x4 exp4(f32x4 v) {
    f32x4 r;
    r.x = __expf(v.x); r.y = __expf(v.y); r.z = __expf(v.z); r.w = __expf(v.w);
    return r;
}

// ---------------- CSR build ----------------

__global__ void hist_kernel(const int* __restrict__ dst, int* __restrict__ counts, int E, int Nn) {
    int i = blockIdx.x * blockDim.x + threadIdx.x;
    int tot = E + Nn;
    if (i < tot) {
        int d = (i < E) ? dst[i] : (i - E);
        atomicAdd(&counts[d], 1);
    }
}

__global__ void scan1_kernel(const int* __restrict__ counts, int* __restrict__ partial,
                             int* __restrict__ blockSums, int Nn) {
    __shared__ int sh[1024];
    int b = blockIdx.x, t = threadIdx.x;
    int base = b * 1024;
    int orig[4];
    for (int r = 0; r < 4; r++) {
        int i = t + r * 256;
        int v = (base + i < Nn) ? counts[base + i] : 0;
        orig[r] = v;
        sh[i] = v;
    }
    __syncthreads();
    for (int off = 1; off < 1024; off <<= 1) {
        int vals[4];
        for (int r = 0; r < 4; r++) { int i = t + r * 256; vals[r] = (i >= off) ? sh[i - off] : 0; }
        __syncthreads();
        for (int r = 0; r < 4; r++) { int i = t + r * 256; sh[i] += vals[r]; }
        __syncthreads();
    }
    for (int r = 0; r < 4; r++) {
        int i = t + r * 256;
        if (base + i < Nn) partial[base + i] = sh[i] - orig[r];
    }
    if (t == 0) blockSums[b] = sh[1023];
}

__global__ void scan2_kernel(int* __restrict__ blockSums, int nb) {
    if (threadIdx.x == 0 && blockIdx.x == 0) {
        int s = 0;
        for (int i = 0; i < nb; i++) { int v = blockSums[i]; blockSums[i] = s; s += v; }
    }
}

__global__ void finalize_kernel(const int* __restrict__ partial, const int* __restrict__ blockOff,
                                int* __restrict__ row_ptr, int Nn, int Etot) {
    int i = blockIdx.x * blockDim.x + threadIdx.x;
    if (i < Nn) row_ptr[i] = partial[i] + blockOff[i >> 10];
    if (i == 0) row_ptr[Nn] = Etot;
}

__global__ void scatter_kernel(const int* __restrict__ srcE, const int* __restrict__ dstE,
                               const int* __restrict__ row_ptr, int* __restrict__ fill,
                               int* __restrict__ srcs, int E, int Nn) {
    int i = blockIdx.x * blockDim.x + threadIdx.x;
    int tot = E + Nn;
    if (i < tot) {
        int s, d;
        if (i < E) { s = srcE[i]; d = dstE[i]; }
        else       { s = d = i - E; }
        int pos = row_ptr[d] + atomicAdd(&fill[d], 1);
        srcs[pos] = s;
    }
}

// ---------------- fp32 -> split bf16 (hi|lo) conversion ----------------
// A2[r][0..255] = bf16_trunc(x), A2[r][256..511] = bf16_trunc(x - hi)
__global__ void convertA_kernel(const float* __restrict__ X, unsigned short* __restrict__ A2,
                                int row_base, int rows) {
    int t = blockIdx.x * 256 + threadIdx.x;
    if (t >= rows * 64) return;
    int r = t >> 6, c4 = t & 63;
    f32x4 v = *((const f32x4*)(X + ((size_t)(row_base + r) << 8)) + c4);
    unsigned int bx = __float_as_uint(v.x), by = __float_as_uint(v.y),
                 bz = __float_as_uint(v.z), bw = __float_as_uint(v.w);
    u16x4 hi; hi.x = (unsigned short)(bx >> 16); hi.y = (unsigned short)(by >> 16);
              hi.z = (unsigned short)(bz >> 16); hi.w = (unsigned short)(bw >> 16);
    f32x4 hf;
    hf.x = __uint_as_float(bx & 0xffff0000u); hf.y = __uint_as_float(by & 0xffff0000u);
    hf.z = __uint_as_float(bz & 0xffff0000u); hf.w = __uint_as_float(bw & 0xffff0000u);
    f32x4 lo = v - hf;
    u16x4 lv;
    lv.x = (unsigned short)(__float_as_uint(lo.x) >> 16);
    lv.y = (unsigned short)(__float_as_uint(lo.y) >> 16);
    lv.z = (unsigned short)(__float_as_uint(lo.z) >> 16);
    lv.w = (unsigned short)(__float_as_uint(lo.w) >> 16);
    *(u16x4*)(A2 + (size_t)r * 512 + c4 * 4) = hi;
    *(u16x4*)(A2 + (size_t)r * 512 + 256 + c4 * 4) = lv;
}

// W[k][n] fp32 -> Bt[n][k] hi, Bt[n][256+k] lo, Bt[n][512+k] hi   (Bt: [256][768] bf16)
__global__ void transposeW_kernel(const float* __restrict__ W, unsigned short* __restrict__ Bt) {
    int t = blockIdx.x * 256 + threadIdx.x;   // 65536 threads
    int n = t >> 8, k = t & 255;
    float v = W[k * 256 + n];
    unsigned int u = __float_as_uint(v);
    unsigned short hi = (unsigned short)(u >> 16);
    float hf = __uint_as_float(u & 0xffff0000u);
    unsigned short lo = (unsigned short)(__float_as_uint(v - hf) >> 16);
    Bt[(size_t)n * 768 + k] = hi;
    Bt[(size_t)n * 768 + 256 + k] = lo;
    Bt[(size_t)n * 768 + 512 + k] = hi;
}

// ---------------- split-bf16 MFMA GEMM ----------------
// C[rows,256] += A2(hi|lo) x Bt over K=768 bf16 (hi*hi + hi*lo + lo*hi).
// 128x128 tile, BK=64, 4 waves (2x2), mfma_f32_16x16x32_bf16.
__global__ __launch_bounds__(256) void gemm_kernel(const unsigned short* __restrict__ A2,
                                                   const unsigned short* __restrict__ Bt,
                                                   float* __restrict__ C,
                                                   int rows, int row_base) {
    __shared__ __align__(128) unsigned char smem[32768];
    unsigned short* As = (unsigned short*)smem;            // [128][64] bf16, 8x16B chunks/row
    unsigned short* Bs = (unsigned short*)(smem + 16384);  // [128][64]

    int tid = threadIdx.x;
    int lane = tid & 63, wid = tid >> 6;
    int wr = wid >> 1, wc = wid & 1;
    int bm = blockIdx.x * 128;
    int bn = blockIdx.y * 128;

    f32x4 zero4 = {0.f, 0.f, 0.f, 0.f};
    f32x4 acc[4][4];
#pragma unroll
    for (int i = 0; i < 4; i++)
#pragma unroll
        for (int j = 0; j < 4; j++) acc[i][j] = zero4;

    int sr = tid >> 3;   // 0..31 (row within a 32-row staging call)
    int sc = tid & 7;    // chunk 0..7

    for (int kt = 0; kt < 768; kt += 64) {
        int kA = (kt < 256) ? kt : kt - 256;
#pragma unroll
        for (int q = 0; q < 4; q++) {
            int rt = q * 32 + sr;
            int gr = bm + rt; if (gr >= rows) gr = rows - 1;
            int cg = sc ^ (rt & 7);
            const unsigned short* gp = A2 + (size_t)gr * 512 + kA + cg * 8;
            unsigned short* lp = As + rt * 64 + sc * 8;
            __builtin_amdgcn_global_load_lds(
                (__attribute__((address_space(1))) void*)(uintptr_t)gp,
                (__attribute__((address_space(3))) void*)lp, 16, 0, 0);
        }
#pragma unroll
        for (int q = 0; q < 4; q++) {
            int rt = q * 32 + sr;
            int gn = bn + rt;   // always < 256
            int cg = sc ^ (rt & 7);
            const unsigned short* gp = Bt + (size_t)gn * 768 + kt + cg * 8;
            unsigned short* lp = Bs + rt * 64 + sc * 8;
            __builtin_amdgcn_global_load_lds(
                (__attribute__((address_space(1))) void*)(uintptr_t)gp,
                (__attribute__((address_space(3))) void*)lp, 16, 0, 0);
        }
        __syncthreads();
#pragma unroll
        for (int ks = 0; ks < 2; ks++) {
            bf16x8 af[4], bfr[4];
#pragma unroll
            for (int f = 0; f < 4; f++) {
                int r = wr * 64 + f * 16 + (lane & 15);
                int c = (ks * 4 + (lane >> 4)) ^ (r & 7);
                af[f] = *(const bf16x8*)(As + r * 64 + c * 8);
                int rb = wc * 64 + f * 16 + (lane & 15);
                int cb = (ks * 4 + (lane >> 4)) ^ (rb & 7);
                bfr[f] = *(const bf16x8*)(Bs + rb * 64 + cb * 8);
            }
#pragma unroll
            for (int i = 0; i < 4; i++)
#pragma unroll
                for (int j = 0; j < 4; j++)
                    acc[i][j] = __builtin_amdgcn_mfma_f32_16x16x32_bf16(af[i], bfr[j], acc[i][j], 0, 0, 0);
        }
        __syncthreads();
    }

    int r0 = wr * 64 + (lane >> 4) * 4;
    int c0 = wc * 64 + (lane & 15);
#pragma unroll
    for (int i = 0; i < 4; i++) {
#pragma unroll
        for (int j = 0; j < 4; j++) {
#pragma unroll
            for (int rg = 0; rg < 4; rg++) {
                int lr = bm + r0 + i * 16 + rg;
                if (lr < rows) {
                    int col = bn + c0 + j * 16;
                    C[(size_t)(row_base + lr) * 256 + col] = acc[i][j][rg];
                }
            }
        }
    }
}

// ---------------- attention coefficients (wave per node, float4 lanes) ----------------
__global__ __launch_bounds__(256) void attn_kernel(const float* __restrict__ G,
                                                   const float* __restrict__ att_s,
                                                   const float* __restrict__ att_d,
                                                   float* __restrict__ a_src,
                                                   float* __restrict__ a_dst, int N) {
    int wv = threadIdx.x >> 6, lane = threadIdx.x & 63;
    int n = blockIdx.x * 4 + wv;
    if (n >= N) return;
    f32x4 g = *((const f32x4*)G + (size_t)n * 64 + lane);
    f32x4 s4 = ((const f32x4*)att_s)[lane];
    f32x4 d4 = ((const f32x4*)att_d)[lane];
    f32x4 p = g * s4, q = g * d4;
    float ps = p.x + p.y + p.z + p.w;
    float pd = q.x + q.y + q.z + q.w;
#pragma unroll
    for (int off = 1; off < 16; off <<= 1) {
        ps += __shfl_xor(ps, off);
        pd += __shfl_xor(pd, off);
    }
    if ((lane & 15) == 0) {
        int head = lane >> 4;
        a_src[n * 4 + head] = ps;
        a_dst[n * 4 + head] = pd;
    }
}

// ---------------- edge softmax + aggregation (wave per node, float4 lanes) ----------------
__global__ __launch_bounds__(256) void agg_kernel(const float* __restrict__ G,
                                                  const float* __restrict__ a_src,
                                                  const float* __restrict__ a_dst,
                                                  const int* __restrict__ row_ptr,
                                                  const int* __restrict__ srcs,
                                                  const float* __restrict__ bias,
                                                  float* __restrict__ out, int do_relu, int N) {
    __shared__ float e_lds[4][4][68];
    __shared__ int s_lds[4][64];
    int wv = threadIdx.x >> 6, lane = threadIdx.x & 63;
    int n = blockIdx.x * 4 + wv;
    if (n >= N) return;
    int head = lane >> 4;

    int start = row_ptr[n], end = row_ptr[n + 1];
    const f32x4* G4 = (const f32x4*)G;
    const f32x4* as4p = (const f32x4*)a_src;
    f32x4 adn4 = *(const f32x4*)(a_dst + (size_t)n * 4);

    // pass 1: per-head max over incoming edges (all 4 heads per lane)
    f32x4 m4 = {-1e30f, -1e30f, -1e30f, -1e30f};
    for (int e = start + lane; e < end; e += 64) {
        int s = srcs[e];
        m4 = max4(m4, lky4(as4p[s] + adn4));
    }
#pragma unroll
    for (int off = 32; off; off >>= 1) {
        m4.x = fmaxf(m4.x, __shfl_xor(m4.x, off));
        m4.y = fmaxf(m4.y, __shfl_xor(m4.y, off));
        m4.z = fmaxf(m4.z, __shfl_xor(m4.z, off));
        m4.w = fmaxf(m4.w, __shfl_xor(m4.w, off));
    }

    f32x4 acc = {0.f, 0.f, 0.f, 0.f};
    float denom = 0.f;

    for (int c0 = start; c0 < end; c0 += 64) {
        int cnt = min(64, end - c0);
        if (lane < cnt) {
            int s = srcs[c0 + lane];
            s_lds[wv][lane] = s;
            f32x4 ev = exp4(lky4(as4p[s] + adn4) - m4);
            e_lds[wv][0][lane] = ev.x;
            e_lds[wv][1][lane] = ev.y;
            e_lds[wv][2][lane] = ev.z;
            e_lds[wv][3][lane] = ev.w;
        }
        for (int j = 0; j < cnt; ++j) {
            float wgt = e_lds[wv][head][j];
            int sj = s_lds[wv][j];
            f32x4 g = G4[(size_t)sj * 64 + lane];
            denom += wgt;
            acc += g * wgt;
        }
    }

    f32x4 r = acc * (1.0f / denom) + ((const f32x4*)bias)[lane];
    if (do_relu) r = max4(r, (f32x4){0.f, 0.f, 0.f, 0.f});
    *((f32x4*)out + (size_t)n * 64 + lane) = r;
}

// ---------------- launch ----------------

extern "C" void kernel_launch(void* const* d_in, const int* in_sizes, int n_in,
                              void* d_out, int out_size, void* d_ws, size_t ws_size,
                              hipStream_t stream) {
    const float* x   = (const float*)d_in[0];
    const int*   ei  = (const int*)d_in[1];
    const float* W1  = (const float*)d_in[2];
    const float* as1 = (const float*)d_in[3];
    const float* ad1 = (const float*)d_in[4];
    const float* b1  = (const float*)d_in[5];
    const float* W2  = (const float*)d_in[6];
    const float* as2 = (const float*)d_in[7];
    const float* ad2 = (const float*)d_in[8];
    const float* b2  = (const float*)d_in[9];

    int N = in_sizes[0] / 256;
    int E = in_sizes[1] / 2;
    int Etot = E + N;
    const int* srcE = ei;
    const int* dstE = ei + E;
    float* out = (float*)d_out;

    char* w = (char*)d_ws;
    size_t used = 0;
    auto alloc = [&](size_t bytes) -> char* {
        char* p = w + used;
        used += (bytes + 255) & ~(size_t)255;
        return p;
    };
    float* G       = (float*)alloc((size_t)N * 256 * 4);
    float* a_src   = (float*)alloc((size_t)N * 4 * 4);
    float* a_dst   = (float*)alloc((size_t)N * 4 * 4);
    int* counts    = (int*)alloc((size_t)N * 4);
    int* partial   = (int*)alloc((size_t)N * 4);
    int* fill      = (int*)alloc((size_t)N * 4);
    int* row_ptr   = (int*)alloc(((size_t)N + 1) * 4);
    int* srcs      = (int*)alloc((size_t)Etot * 4);
    int* blockSums = (int*)alloc(256 * 4);
    unsigned short* Bt = (unsigned short*)alloc((size_t)256 * 768 * 2);
    unsigned short* A2 = (unsigned short*)(w + used);

    size_t avail = (ws_size > used) ? (ws_size - used) : 0;
    long long cap = (long long)(avail / 1024);   // bytes per A2 row = 512*2
    int rows_cap = (cap >= N) ? N : (int)(cap & ~127LL);
    if (rows_cap < 128) rows_cap = 128;          // assume ws is at least this big

    hipMemsetAsync(counts, 0, (size_t)N * 4, stream);
    hipMemsetAsync(fill, 0, (size_t)N * 4, stream);

    hist_kernel<<<(Etot + 255) / 256, 256, 0, stream>>>(dstE, counts, E, N);
    int nScanBlocks = (N + 1023) / 1024;
    scan1_kernel<<<nScanBlocks, 256, 0, stream>>>(counts, partial, blockSums, N);
    scan2_kernel<<<1, 64, 0, stream>>>(blockSums, nScanBlocks);
    finalize_kernel<<<(N + 255) / 256, 256, 0, stream>>>(partial, blockSums, row_ptr, N, Etot);
    scatter_kernel<<<(Etot + 255) / 256, 256, 0, stream>>>(srcE, dstE, row_ptr, fill, srcs, E, N);

    int nodeBlocks = (N + 3) / 4;

    for (int layer = 0; layer < 2; layer++) {
        const float* Wl  = layer == 0 ? W1 : W2;
        const float* asl = layer == 0 ? as1 : as2;
        const float* adl = layer == 0 ? ad1 : ad2;
        const float* bl  = layer == 0 ? b1 : b2;
        const float* feat = layer == 0 ? x : out;

        transposeW_kernel<<<256, 256, 0, stream>>>(Wl, Bt);
        for (int rb = 0; rb < N; rb += rows_cap) {
            int rows = min(rows_cap, N - rb);
            convertA_kernel<<<(rows * 64 + 255) / 256, 256, 0, stream>>>(feat, A2, rb, rows);
            dim3 gg((rows + 127) / 128, 2);
            gemm_kernel<<<gg, 256, 0, stream>>>(A2, Bt, G, rows, rb);
        }
        attn_kernel<<<nodeBlocks, 256, 0, stream>>>(G, asl, adl, a_src, a_dst, N);
        agg_kernel<<<nodeBlocks, 256, 0, stream>>>(G, a_src, a_dst, row_ptr, srcs, bl, out,
                                                   layer == 0 ? 1 : 0, N);
    }
}

// Round 3
// 371.756 us; speedup vs baseline: 1.7058x; 1.3391x over previous
//
#include <hip/hip_runtime.h>
#include <math.h>

#define NEG_SLOPE 0.2f

typedef __attribute__((ext_vector_type(8))) short bf16x8;
typedef __attribute__((ext_vector_type(4))) float f32x4;
typedef __attribute__((ext_vector_type(4))) unsigned short u16x4;
typedef __attribute__((ext_vector_type(8))) unsigned short u16x8;

static __device__ __forceinline__ f32x4 lky4(f32x4 v) {
    f32x4 r;
    r.x = v.x >= 0.f ? v.x : NEG_SLOPE * v.x;
    r.y = v.y >= 0.f ? v.y : NEG_SLOPE * v.y;
    r.z = v.z >= 0.f ? v.z : NEG_SLOPE * v.z;
    r.w = v.w >= 0.f ? v.w : NEG_SLOPE * v.w;
    return r;
}
static __device__ __forceinline__ f32x4 max4(f32x4 a, f32x4 b) {
    f32x4 r;
    r.x = fmaxf(a.x, b.x); r.y = fmaxf(a.y, b.y);
    r.z = fmaxf(a.z, b.z); r.w = fmaxf(a.w, b.w);
    return r;
}
static __device__ __forceinline__ f32x4 exp4(f32x4 v) {
    f32x4 r;
    r.x = __expf(v.x); r.y = __expf(v.y); r.z = __expf(v.z); r.w = __expf(v.w);
    return r;
}
static __device__ __forceinline__ float bf2f(unsigned short u) {
    return __uint_as_float(((unsigned int)u) << 16);
}
static __device__ __forceinline__ unsigned short f2bf_rne(float f) {
    unsigned int u = __float_as_uint(f);
    u += 0x7fffu + ((u >> 16) & 1u);
    return (unsigned short)(u >> 16);
}

// ---------------- CSR build ----------------

__global__ void hist_kernel(const int* __restrict__ dst, int* __restrict__ counts, int E, int Nn) {
    int i = blockIdx.x * blockDim.x + threadIdx.x;
    int tot = E + Nn;
    if (i < tot) {
        int d = (i < E) ? dst[i] : (i - E);
        atomicAdd(&counts[d], 1);
    }
}

__global__ void scan1_kernel(const int* __restrict__ counts, int* __restrict__ partial,
                             int* __restrict__ blockSums, int Nn) {
    __shared__ int sh[1024];
    int b = blockIdx.x, t = threadIdx.x;
    int base = b * 1024;
    int orig[4];
    for (int r = 0; r < 4; r++) {
        int i = t + r * 256;
        int v = (base + i < Nn) ? counts[base + i] : 0;
        orig[r] = v;
        sh[i] = v;
    }
    __syncthreads();
    for (int off = 1; off < 1024; off <<= 1) {
        int vals[4];
        for (int r = 0; r < 4; r++) { int i = t + r * 256; vals[r] = (i >= off) ? sh[i - off] : 0; }
        __syncthreads();
        for (int r = 0; r < 4; r++) { int i = t + r * 256; sh[i] += vals[r]; }
        __syncthreads();
    }
    for (int r = 0; r < 4; r++) {
        int i = t + r * 256;
        if (base + i < Nn) partial[base + i] = sh[i] - orig[r];
    }
    if (t == 0) blockSums[b] = sh[1023];
}

__global__ void scan2_kernel(int* __restrict__ blockSums, int nb) {
    if (threadIdx.x == 0 && blockIdx.x == 0) {
        int s = 0;
        for (int i = 0; i < nb; i++) { int v = blockSums[i]; blockSums[i] = s; s += v; }
    }
}

__global__ void finalize_kernel(const int* __restrict__ partial, const int* __restrict__ blockOff,
                                int* __restrict__ row_ptr, int Nn, int Etot) {
    int i = blockIdx.x * blockDim.x + threadIdx.x;
    if (i < Nn) row_ptr[i] = partial[i] + blockOff[i >> 10];
    if (i == 0) row_ptr[Nn] = Etot;
}

__global__ void scatter_kernel(const int* __restrict__ srcE, const int* __restrict__ dstE,
                               const int* __restrict__ row_ptr, int* __restrict__ fill,
                               int* __restrict__ srcs, int E, int Nn) {
    int i = blockIdx.x * blockDim.x + threadIdx.x;
    int tot = E + Nn;
    if (i < tot) {
        int s, d;
        if (i < E) { s = srcE[i]; d = dstE[i]; }
        else       { s = d = i - E; }
        int pos = row_ptr[d] + atomicAdd(&fill[d], 1);
        srcs[pos] = s;
    }
}

// ---------------- fp32 -> split bf16 (hi|lo) conversion ----------------
__global__ void convertA_kernel(const float* __restrict__ X, unsigned short* __restrict__ A2,
                                int rows) {
    int t = blockIdx.x * 256 + threadIdx.x;
    if (t >= rows * 64) return;
    int r = t >> 6, c4 = t & 63;
    f32x4 v = *((const f32x4*)(X + ((size_t)r << 8)) + c4);
    unsigned int bx = __float_as_uint(v.x), by = __float_as_uint(v.y),
                 bz = __float_as_uint(v.z), bw = __float_as_uint(v.w);
    u16x4 hi; hi.x = (unsigned short)(bx >> 16); hi.y = (unsigned short)(by >> 16);
              hi.z = (unsigned short)(bz >> 16); hi.w = (unsigned short)(bw >> 16);
    f32x4 hf;
    hf.x = __uint_as_float(bx & 0xffff0000u); hf.y = __uint_as_float(by & 0xffff0000u);
    hf.z = __uint_as_float(bz & 0xffff0000u); hf.w = __uint_as_float(bw & 0xffff0000u);
    f32x4 lo = v - hf;
    u16x4 lv;
    lv.x = (unsigned short)(__float_as_uint(lo.x) >> 16);
    lv.y = (unsigned short)(__float_as_uint(lo.y) >> 16);
    lv.z = (unsigned short)(__float_as_uint(lo.z) >> 16);
    lv.w = (unsigned short)(__float_as_uint(lo.w) >> 16);
    *(u16x4*)(A2 + (size_t)r * 512 + c4 * 4) = hi;
    *(u16x4*)(A2 + (size_t)r * 512 + 256 + c4 * 4) = lv;
}

// W[k][n] fp32 -> Bt[n][k] hi, Bt[n][256+k] lo, Bt[n][512+k] hi   (Bt: [256][768] bf16)
__global__ void transposeW_kernel(const float* __restrict__ W, unsigned short* __restrict__ Bt) {
    int t = blockIdx.x * 256 + threadIdx.x;   // 65536 threads
    int n = t >> 8, k = t & 255;
    float v = W[k * 256 + n];
    unsigned int u = __float_as_uint(v);
    unsigned short hi = (unsigned short)(u >> 16);
    float hf = __uint_as_float(u & 0xffff0000u);
    unsigned short lo = (unsigned short)(__float_as_uint(v - hf) >> 16);
    Bt[(size_t)n * 768 + k] = hi;
    Bt[(size_t)n * 768 + 256 + k] = lo;
    Bt[(size_t)n * 768 + 512 + k] = hi;
}

// ---------------- split-bf16 MFMA GEMM ----------------
// Gb[rows,256] (bf16, RNE) = A2(hi|lo) x Bt over K=768 bf16 (hi*hi + hi*lo + lo*hi).
__global__ __launch_bounds__(256) void gemm_kernel(const unsigned short* __restrict__ A2,
                                                   const unsigned short* __restrict__ Bt,
                                                   unsigned short* __restrict__ Gb,
                                                   int rows) {
    __shared__ __align__(128) unsigned char smem[32768];
    unsigned short* As = (unsigned short*)smem;            // [128][64] bf16
    unsigned short* Bs = (unsigned short*)(smem + 16384);  // [128][64]

    int tid = threadIdx.x;
    int lane = tid & 63, wid = tid >> 6;
    int wr = wid >> 1, wc = wid & 1;
    int bm = blockIdx.x * 128;
    int bn = blockIdx.y * 128;

    f32x4 zero4 = {0.f, 0.f, 0.f, 0.f};
    f32x4 acc[4][4];
#pragma unroll
    for (int i = 0; i < 4; i++)
#pragma unroll
        for (int j = 0; j < 4; j++) acc[i][j] = zero4;

    int sr = tid >> 3;   // 0..31
    int sc = tid & 7;    // chunk 0..7

    for (int kt = 0; kt < 768; kt += 64) {
        int kA = (kt < 256) ? kt : kt - 256;
#pragma unroll
        for (int q = 0; q < 4; q++) {
            int rt = q * 32 + sr;
            int gr = bm + rt; if (gr >= rows) gr = rows - 1;
            int cg = sc ^ (rt & 7);
            const unsigned short* gp = A2 + (size_t)gr * 512 + kA + cg * 8;
            unsigned short* lp = As + rt * 64 + sc * 8;
            __builtin_amdgcn_global_load_lds(
                (__attribute__((address_space(1))) void*)(uintptr_t)gp,
                (__attribute__((address_space(3))) void*)lp, 16, 0, 0);
        }
#pragma unroll
        for (int q = 0; q < 4; q++) {
            int rt = q * 32 + sr;
            int gn = bn + rt;
            int cg = sc ^ (rt & 7);
            const unsigned short* gp = Bt + (size_t)gn * 768 + kt + cg * 8;
            unsigned short* lp = Bs + rt * 64 + sc * 8;
            __builtin_amdgcn_global_load_lds(
                (__attribute__((address_space(1))) void*)(uintptr_t)gp,
                (__attribute__((address_space(3))) void*)lp, 16, 0, 0);
        }
        __syncthreads();
#pragma unroll
        for (int ks = 0; ks < 2; ks++) {
            bf16x8 af[4], bfr[4];
#pragma unroll
            for (int f = 0; f < 4; f++) {
                int r = wr * 64 + f * 16 + (lane & 15);
                int c = (ks * 4 + (lane >> 4)) ^ (r & 7);
                af[f] = *(const bf16x8*)(As + r * 64 + c * 8);
                int rb = wc * 64 + f * 16 + (lane & 15);
                int cb = (ks * 4 + (lane >> 4)) ^ (rb & 7);
                bfr[f] = *(const bf16x8*)(Bs + rb * 64 + cb * 8);
            }
#pragma unroll
            for (int i = 0; i < 4; i++)
#pragma unroll
                for (int j = 0; j < 4; j++)
                    acc[i][j] = __builtin_amdgcn_mfma_f32_16x16x32_bf16(af[i], bfr[j], acc[i][j], 0, 0, 0);
        }
        __syncthreads();
    }

    int r0 = wr * 64 + (lane >> 4) * 4;
    int c0 = wc * 64 + (lane & 15);
#pragma unroll
    for (int i = 0; i < 4; i++) {
#pragma unroll
        for (int j = 0; j < 4; j++) {
#pragma unroll
            for (int rg = 0; rg < 4; rg++) {
                int lr = bm + r0 + i * 16 + rg;
                if (lr < rows) {
                    int col = bn + c0 + j * 16;
                    Gb[(size_t)lr * 256 + col] = f2bf_rne(acc[i][j][rg]);
                }
            }
        }
    }
}

// ---------------- attention coefficients (wave per node, bf16 G) ----------------
__global__ __launch_bounds__(256) void attn_kernel(const unsigned short* __restrict__ Gb,
                                                   const float* __restrict__ att_s,
                                                   const float* __restrict__ att_d,
                                                   float* __restrict__ a_src,
                                                   float* __restrict__ a_dst, int N) {
    int wv = threadIdx.x >> 6, lane = threadIdx.x & 63;
    int n = blockIdx.x * 4 + wv;
    if (n >= N) return;
    u16x4 g4 = *(const u16x4*)(Gb + (size_t)n * 256 + lane * 4);
    f32x4 g;
    g.x = bf2f(g4.x); g.y = bf2f(g4.y); g.z = bf2f(g4.z); g.w = bf2f(g4.w);
    f32x4 s4 = ((const f32x4*)att_s)[lane];
    f32x4 d4 = ((const f32x4*)att_d)[lane];
    f32x4 p = g * s4, q = g * d4;
    float ps = p.x + p.y + p.z + p.w;
    float pd = q.x + q.y + q.z + q.w;
#pragma unroll
    for (int off = 1; off < 16; off <<= 1) {
        ps += __shfl_xor(ps, off);
        pd += __shfl_xor(pd, off);
    }
    if ((lane & 15) == 0) {
        int head = lane >> 4;
        a_src[n * 4 + head] = ps;
        a_dst[n * 4 + head] = pd;
    }
}

// ---------------- online-softmax aggregation (wave per node, bf16 gather) ----------------
// outF != null  -> write fp32 (+bias), no relu  (final layer)
// outA2 != null -> write relu(h) as hi/lo bf16 split rows [512] (next layer's GEMM input)
__global__ __launch_bounds__(256) void agg_kernel(const unsigned short* __restrict__ Gb,
                                                  const float* __restrict__ a_src,
                                                  const float* __restrict__ a_dst,
                                                  const int* __restrict__ row_ptr,
                                                  const int* __restrict__ srcs,
                                                  const float* __restrict__ bias,
                                                  float* __restrict__ outF,
                                                  unsigned short* __restrict__ outA2,
                                                  int N) {
    __shared__ float e_lds[4][4][68];
    __shared__ int s_lds[4][64];
    int wv = threadIdx.x >> 6, lane = threadIdx.x & 63;
    int n = blockIdx.x * 4 + wv;
    if (n >= N) return;
    int half = lane >> 5;   // 0/1: which edge of the pair
    int sl = lane & 31;     // feature chunk: 8 floats at sl*8
    int head = sl >> 3;

    int start = row_ptr[n], end = row_ptr[n + 1];
    const f32x4* as4p = (const f32x4*)a_src;
    f32x4 adn4 = *(const f32x4*)(a_dst + (size_t)n * 4);

    f32x4 m4 = {-1e30f, -1e30f, -1e30f, -1e30f};
    float acc[8] = {0.f, 0.f, 0.f, 0.f, 0.f, 0.f, 0.f, 0.f};
    float denom = 0.f;

    for (int c0 = start; c0 < end; c0 += 64) {
        int cnt = min(64, end - c0);
        f32x4 al4 = {-1e30f, -1e30f, -1e30f, -1e30f};
        int s = 0;
        if (lane < cnt) {
            s = srcs[c0 + lane];
            al4 = lky4(as4p[s] + adn4);
        }
        // chunk max (wave-wide), then online rescale
        f32x4 mc = al4;
#pragma unroll
        for (int off = 32; off; off >>= 1) {
            mc.x = fmaxf(mc.x, __shfl_xor(mc.x, off));
            mc.y = fmaxf(mc.y, __shfl_xor(mc.y, off));
            mc.z = fmaxf(mc.z, __shfl_xor(mc.z, off));
            mc.w = fmaxf(mc.w, __shfl_xor(mc.w, off));
        }
        f32x4 mnew = max4(m4, mc);
        f32x4 sc4 = exp4(m4 - mnew);   // first chunk: exp(-inf)=0, acc already 0
        float sch = head == 0 ? sc4.x : head == 1 ? sc4.y : head == 2 ? sc4.z : sc4.w;
#pragma unroll
        for (int k = 0; k < 8; k++) acc[k] *= sch;
        denom *= sch;
        m4 = mnew;

        if (lane < cnt) {
            f32x4 ev = exp4(al4 - m4);
            s_lds[wv][lane] = s;
            e_lds[wv][0][lane] = ev.x;
            e_lds[wv][1][lane] = ev.y;
            e_lds[wv][2][lane] = ev.z;
            e_lds[wv][3][lane] = ev.w;
        }
        for (int j = 0; j < cnt; j += 2) {
            int je = j + half;
            if (je < cnt) {
                float wgt = e_lds[wv][head][je];
                int sj = s_lds[wv][je];
                u16x8 g8 = *(const u16x8*)(Gb + (size_t)sj * 256 + sl * 8);
                denom += wgt;
#pragma unroll
                for (int k = 0; k < 8; k++)
                    acc[k] = fmaf(bf2f(g8[k]), wgt, acc[k]);
            }
        }
    }

    // combine the two half-wave edge sets
#pragma unroll
    for (int k = 0; k < 8; k++) acc[k] += __shfl_xor(acc[k], 32);
    denom += __shfl_xor(denom, 32);

    float rden = 1.0f / denom;
    float r[8];
    const float* bp = bias + sl * 8;
#pragma unroll
    for (int k = 0; k < 8; k++) r[k] = acc[k] * rden + bp[k];

    if (outF) {
        if (half == 0) {
            f32x4 v0 = {r[0], r[1], r[2], r[3]};
            f32x4 v1 = {r[4], r[5], r[6], r[7]};
            f32x4* op = (f32x4*)(outF + (size_t)n * 256 + sl * 8);
            op[0] = v0; op[1] = v1;
        }
    } else {
#pragma unroll
        for (int k = 0; k < 8; k++) r[k] = fmaxf(r[k], 0.f);
        u16x8 v;
        if (half == 0) {
#pragma unroll
            for (int k = 0; k < 8; k++)
                v[k] = (unsigned short)(__float_as_uint(r[k]) >> 16);   // hi (trunc)
            *(u16x8*)(outA2 + (size_t)n * 512 + sl * 8) = v;
        } else {
#pragma unroll
            for (int k = 0; k < 8; k++) {
                unsigned int u = __float_as_uint(r[k]);
                float res = r[k] - __uint_as_float(u & 0xffff0000u);
                v[k] = (unsigned short)(__float_as_uint(res) >> 16);    // lo
            }
            *(u16x8*)(outA2 + (size_t)n * 512 + 256 + sl * 8) = v;
        }
    }
}

// ---------------- launch ----------------

extern "C" void kernel_launch(void* const* d_in, const int* in_sizes, int n_in,
                              void* d_out, int out_size, void* d_ws, size_t ws_size,
                              hipStream_t stream) {
    const float* x   = (const float*)d_in[0];
    const int*   ei  = (const int*)d_in[1];
    const float* W1  = (const float*)d_in[2];
    const float* as1 = (const float*)d_in[3];
    const float* ad1 = (const float*)d_in[4];
    const float* b1  = (const float*)d_in[5];
    const float* W2  = (const float*)d_in[6];
    const float* as2 = (const float*)d_in[7];
    const float* ad2 = (const float*)d_in[8];
    const float* b2  = (const float*)d_in[9];

    int N = in_sizes[0] / 256;
    int E = in_sizes[1] / 2;
    int Etot = E + N;
    const int* srcE = ei;
    const int* dstE = ei + E;

    // A2 (hi|lo split GEMM input, N x 512 bf16 = N*1024 bytes) lives in d_out:
    // same byte size as the N x 256 fp32 output. Final-layer agg overwrites it
    // with the real fp32 output as the last kernel.
    unsigned short* A2 = (unsigned short*)d_out;
    float* out = (float*)d_out;

    char* w = (char*)d_ws;
    size_t used = 0;
    auto alloc = [&](size_t bytes) -> char* {
        char* p = w + used;
        used += (bytes + 255) & ~(size_t)255;
        return p;
    };
    unsigned short* Gb = (unsigned short*)alloc((size_t)N * 256 * 2);  // bf16 features
    float* a_src   = (float*)alloc((size_t)N * 4 * 4);
    float* a_dst   = (float*)alloc((size_t)N * 4 * 4);
    int* counts    = (int*)alloc((size_t)N * 4);
    int* partial   = (int*)alloc((size_t)N * 4);
    int* fill      = (int*)alloc((size_t)N * 4);
    int* row_ptr   = (int*)alloc(((size_t)N + 1) * 4);
    int* srcs      = (int*)alloc((size_t)Etot * 4);
    int* blockSums = (int*)alloc(256 * 4);
    unsigned short* Bt = (unsigned short*)alloc((size_t)256 * 768 * 2);

    hipMemsetAsync(counts, 0, (size_t)N * 4, stream);
    hipMemsetAsync(fill, 0, (size_t)N * 4, stream);

    hist_kernel<<<(Etot + 255) / 256, 256, 0, stream>>>(dstE, counts, E, N);
    int nScanBlocks = (N + 1023) / 1024;
    scan1_kernel<<<nScanBlocks, 256, 0, stream>>>(counts, partial, blockSums, N);
    scan2_kernel<<<1, 64, 0, stream>>>(blockSums, nScanBlocks);
    finalize_kernel<<<(N + 255) / 256, 256, 0, stream>>>(partial, blockSums, row_ptr, N, Etot);
    scatter_kernel<<<(Etot + 255) / 256, 256, 0, stream>>>(srcE, dstE, row_ptr, fill, srcs, E, N);

    int nodeBlocks = (N + 3) / 4;
    dim3 gg((N + 127) / 128, 2);

    // layer 1
    convertA_kernel<<<(N * 64 + 255) / 256, 256, 0, stream>>>(x, A2, N);
    transposeW_kernel<<<256, 256, 0, stream>>>(W1, Bt);
    gemm_kernel<<<gg, 256, 0, stream>>>(A2, Bt, Gb, N);
    attn_kernel<<<nodeBlocks, 256, 0, stream>>>(Gb, as1, ad1, a_src, a_dst, N);
    agg_kernel<<<nodeBlocks, 256, 0, stream>>>(Gb, a_src, a_dst, row_ptr, srcs, b1,
                                               nullptr, A2, N);   // relu + hi/lo split

    // layer 2
    transposeW_kernel<<<256, 256, 0, stream>>>(W2, Bt);
    gemm_kernel<<<gg, 256, 0, stream>>>(A2, Bt, Gb, N);
    attn_kernel<<<nodeBlocks, 256, 0, stream>>>(Gb, as2, ad2, a_src, a_dst, N);
    agg_kernel<<<nodeBlocks, 256, 0, stream>>>(Gb, a_src, a_dst, row_ptr, srcs, b2,
                                               out, nullptr, N);  // fp32 final
}

// Round 4
// 340.029 us; speedup vs baseline: 1.8650x; 1.0933x over previous
//
#include <hip/hip_runtime.h>
#include <math.h>

#define NEG_SLOPE 0.2f

typedef __attribute__((ext_vector_type(8))) short bf16x8;
typedef __attribute__((ext_vector_type(4))) float f32x4;
typedef __attribute__((ext_vector_type(4))) unsigned short u16x4;
typedef __attribute__((ext_vector_type(8))) unsigned short u16x8;

static __device__ __forceinline__ f32x4 lky4(f32x4 v) {
    f32x4 r;
    r.x = v.x >= 0.f ? v.x : NEG_SLOPE * v.x;
    r.y = v.y >= 0.f ? v.y : NEG_SLOPE * v.y;
    r.z = v.z >= 0.f ? v.z : NEG_SLOPE * v.z;
    r.w = v.w >= 0.f ? v.w : NEG_SLOPE * v.w;
    return r;
}
static __device__ __forceinline__ f32x4 max4(f32x4 a, f32x4 b) {
    f32x4 r;
    r.x = fmaxf(a.x, b.x); r.y = fmaxf(a.y, b.y);
    r.z = fmaxf(a.z, b.z); r.w = fmaxf(a.w, b.w);
    return r;
}
static __device__ __forceinline__ f32x4 exp4(f32x4 v) {
    f32x4 r;
    r.x = __expf(v.x); r.y = __expf(v.y); r.z = __expf(v.z); r.w = __expf(v.w);
    return r;
}
static __device__ __forceinline__ float bf2f(unsigned short u) {
    return __uint_as_float(((unsigned int)u) << 16);
}
static __device__ __forceinline__ unsigned short f2bf_rne(float f) {
    unsigned int u = __float_as_uint(f);
    u += 0x7fffu + ((u >> 16) & 1u);
    return (unsigned short)(u >> 16);
}

// ---------------- CSR build ----------------

__global__ void hist_kernel(const int* __restrict__ dst, int* __restrict__ counts, int E, int Nn) {
    int i = blockIdx.x * blockDim.x + threadIdx.x;
    int tot = E + Nn;
    if (i < tot) {
        int d = (i < E) ? dst[i] : (i - E);
        atomicAdd(&counts[d], 1);
    }
}

__global__ void scan1_kernel(const int* __restrict__ counts, int* __restrict__ partial,
                             int* __restrict__ blockSums, int Nn) {
    __shared__ int sh[1024];
    int b = blockIdx.x, t = threadIdx.x;
    int base = b * 1024;
    int orig[4];
    for (int r = 0; r < 4; r++) {
        int i = t + r * 256;
        int v = (base + i < Nn) ? counts[base + i] : 0;
        orig[r] = v;
        sh[i] = v;
    }
    __syncthreads();
    for (int off = 1; off < 1024; off <<= 1) {
        int vals[4];
        for (int r = 0; r < 4; r++) { int i = t + r * 256; vals[r] = (i >= off) ? sh[i - off] : 0; }
        __syncthreads();
        for (int r = 0; r < 4; r++) { int i = t + r * 256; sh[i] += vals[r]; }
        __syncthreads();
    }
    for (int r = 0; r < 4; r++) {
        int i = t + r * 256;
        if (base + i < Nn) partial[base + i] = sh[i] - orig[r];
    }
    if (t == 0) blockSums[b] = sh[1023];
}

__global__ void scan2_kernel(int* __restrict__ blockSums, int nb) {
    if (threadIdx.x == 0 && blockIdx.x == 0) {
        int s = 0;
        for (int i = 0; i < nb; i++) { int v = blockSums[i]; blockSums[i] = s; s += v; }
    }
}

__global__ void finalize_kernel(const int* __restrict__ partial, const int* __restrict__ blockOff,
                                int* __restrict__ row_ptr, int Nn, int Etot) {
    int i = blockIdx.x * blockDim.x + threadIdx.x;
    if (i < Nn) row_ptr[i] = partial[i] + blockOff[i >> 10];
    if (i == 0) row_ptr[Nn] = Etot;
}

__global__ void scatter_kernel(const int* __restrict__ srcE, const int* __restrict__ dstE,
                               const int* __restrict__ row_ptr, int* __restrict__ fill,
                               int* __restrict__ srcs, int E, int Nn) {
    int i = blockIdx.x * blockDim.x + threadIdx.x;
    int tot = E + Nn;
    if (i < tot) {
        int s, d;
        if (i < E) { s = srcE[i]; d = dstE[i]; }
        else       { s = d = i - E; }
        int pos = row_ptr[d] + atomicAdd(&fill[d], 1);
        srcs[pos] = s;
    }
}

// ---------------- fp32 -> bf16 RNE ----------------
__global__ void convertA_kernel(const float* __restrict__ X, unsigned short* __restrict__ Ab,
                                int rows) {
    int t = blockIdx.x * 256 + threadIdx.x;
    if (t >= rows * 64) return;
    int r = t >> 6, c4 = t & 63;
    f32x4 v = *((const f32x4*)(X + ((size_t)r << 8)) + c4);
    u16x4 o;
    o.x = f2bf_rne(v.x); o.y = f2bf_rne(v.y);
    o.z = f2bf_rne(v.z); o.w = f2bf_rne(v.w);
    *(u16x4*)(Ab + (size_t)r * 256 + c4 * 4) = o;
}

// W[k][n] fp32 -> Bt[n][k] = rne(w), Bt[n][256+k] = rne(w - hi)   (Bt: [256][512] bf16)
__global__ void transposeW_kernel(const float* __restrict__ W, unsigned short* __restrict__ Bt) {
    int t = blockIdx.x * 256 + threadIdx.x;   // 65536 threads
    int n = t >> 8, k = t & 255;
    float v = W[k * 256 + n];
    unsigned short hi = f2bf_rne(v);
    float hf = bf2f(hi);
    unsigned short lo = f2bf_rne(v - hf);
    Bt[(size_t)n * 512 + k] = hi;
    Bt[(size_t)n * 512 + 256 + k] = lo;
}

// ---------------- split-bf16 MFMA GEMM ----------------
// Gb[rows,256] (bf16 RNE) = Ab x (Wh + Wl) over K=512 bf16.
__global__ __launch_bounds__(256) void gemm_kernel(const unsigned short* __restrict__ Ab,
                                                   const unsigned short* __restrict__ Bt,
                                                   unsigned short* __restrict__ Gb,
                                                   int rows) {
    __shared__ __align__(128) unsigned char smem[32768];
    unsigned short* As = (unsigned short*)smem;            // [128][64] bf16
    unsigned short* Bs = (unsigned short*)(smem + 16384);  // [128][64]

    int tid = threadIdx.x;
    int lane = tid & 63, wid = tid >> 6;
    int wr = wid >> 1, wc = wid & 1;
    int bm = blockIdx.x * 128;
    int bn = blockIdx.y * 128;

    f32x4 zero4 = {0.f, 0.f, 0.f, 0.f};
    f32x4 acc[4][4];
#pragma unroll
    for (int i = 0; i < 4; i++)
#pragma unroll
        for (int j = 0; j < 4; j++) acc[i][j] = zero4;

    int sr = tid >> 3;   // 0..31
    int sc = tid & 7;    // chunk 0..7

    for (int kt = 0; kt < 512; kt += 64) {
        int kA = kt & 255;
#pragma unroll
        for (int q = 0; q < 4; q++) {
            int rt = q * 32 + sr;
            int gr = bm + rt; if (gr >= rows) gr = rows - 1;
            int cg = sc ^ (rt & 7);
            const unsigned short* gp = Ab + (size_t)gr * 256 + kA + cg * 8;
            unsigned short* lp = As + rt * 64 + sc * 8;
            __builtin_amdgcn_global_load_lds(
                (__attribute__((address_space(1))) void*)(uintptr_t)gp,
                (__attribute__((address_space(3))) void*)lp, 16, 0, 0);
        }
#pragma unroll
        for (int q = 0; q < 4; q++) {
            int rt = q * 32 + sr;
            int gn = bn + rt;
            int cg = sc ^ (rt & 7);
            const unsigned short* gp = Bt + (size_t)gn * 512 + kt + cg * 8;
            unsigned short* lp = Bs + rt * 64 + sc * 8;
            __builtin_amdgcn_global_load_lds(
                (__attribute__((address_space(1))) void*)(uintptr_t)gp,
                (__attribute__((address_space(3))) void*)lp, 16, 0, 0);
        }
        __syncthreads();
#pragma unroll
        for (int ks = 0; ks < 2; ks++) {
            bf16x8 af[4], bfr[4];
#pragma unroll
            for (int f = 0; f < 4; f++) {
                int r = wr * 64 + f * 16 + (lane & 15);
                int c = (ks * 4 + (lane >> 4)) ^ (r & 7);
                af[f] = *(const bf16x8*)(As + r * 64 + c * 8);
                int rb = wc * 64 + f * 16 + (lane & 15);
                int cb = (ks * 4 + (lane >> 4)) ^ (rb & 7);
                bfr[f] = *(const bf16x8*)(Bs + rb * 64 + cb * 8);
            }
#pragma unroll
            for (int i = 0; i < 4; i++)
#pragma unroll
                for (int j = 0; j < 4; j++)
                    acc[i][j] = __builtin_amdgcn_mfma_f32_16x16x32_bf16(af[i], bfr[j], acc[i][j], 0, 0, 0);
        }
        __syncthreads();
    }

    int r0 = wr * 64 + (lane >> 4) * 4;
    int c0 = wc * 64 + (lane & 15);
#pragma unroll
    for (int i = 0; i < 4; i++) {
#pragma unroll
        for (int j = 0; j < 4; j++) {
#pragma unroll
            for (int rg = 0; rg < 4; rg++) {
                int lr = bm + r0 + i * 16 + rg;
                if (lr < rows) {
                    int col = bn + c0 + j * 16;
                    Gb[(size_t)lr * 256 + col] = f2bf_rne(acc[i][j][rg]);
                }
            }
        }
    }
}

// ---------------- attention coefficients (wave per node, bf16 G) ----------------
__global__ __launch_bounds__(256) void attn_kernel(const unsigned short* __restrict__ Gb,
                                                   const float* __restrict__ att_s,
                                                   const float* __restrict__ att_d,
                                                   float* __restrict__ a_src,
                                                   float* __restrict__ a_dst, int N) {
    int wv = threadIdx.x >> 6, lane = threadIdx.x & 63;
    int n = blockIdx.x * 4 + wv;
    if (n >= N) return;
    u16x4 g4 = *(const u16x4*)(Gb + (size_t)n * 256 + lane * 4);
    f32x4 g;
    g.x = bf2f(g4.x); g.y = bf2f(g4.y); g.z = bf2f(g4.z); g.w = bf2f(g4.w);
    f32x4 s4 = ((const f32x4*)att_s)[lane];
    f32x4 d4 = ((const f32x4*)att_d)[lane];
    f32x4 p = g * s4, q = g * d4;
    float ps = p.x + p.y + p.z + p.w;
    float pd = q.x + q.y + q.z + q.w;
#pragma unroll
    for (int off = 1; off < 16; off <<= 1) {
        ps += __shfl_xor(ps, off);
        pd += __shfl_xor(pd, off);
    }
    if ((lane & 15) == 0) {
        int head = lane >> 4;
        a_src[n * 4 + head] = ps;
        a_dst[n * 4 + head] = pd;
    }
}

// ---------------- online-softmax aggregation (wave per node, bf16 gather) ----------------
// outF != null -> fp32 (+bias), no relu (final layer)
// outB != null -> relu(h)+bias as bf16 RNE [256]/row (next layer's GEMM input)
__global__ __launch_bounds__(256) void agg_kernel(const unsigned short* __restrict__ Gb,
                                                  const float* __restrict__ a_src,
                                                  const float* __restrict__ a_dst,
                                                  const int* __restrict__ row_ptr,
                                                  const int* __restrict__ srcs,
                                                  const float* __restrict__ bias,
                                                  float* __restrict__ outF,
                                                  unsigned short* __restrict__ outB,
                                                  int N) {
    __shared__ float e_lds[4][4][68];
    __shared__ int s_lds[4][64];
    int wv = threadIdx.x >> 6, lane = threadIdx.x & 63;
    int n = blockIdx.x * 4 + wv;
    if (n >= N) return;
    int half = lane >> 5;   // 0/1: which edge of the pair
    int sl = lane & 31;     // feature chunk: 8 floats at sl*8
    int head = sl >> 3;

    int start = row_ptr[n], end = row_ptr[n + 1];
    const f32x4* as4p = (const f32x4*)a_src;
    f32x4 adn4 = *(const f32x4*)(a_dst + (size_t)n * 4);

    f32x4 m4 = {-1e30f, -1e30f, -1e30f, -1e30f};
    float acc[8] = {0.f, 0.f, 0.f, 0.f, 0.f, 0.f, 0.f, 0.f};
    float denom = 0.f;

    for (int c0 = start; c0 < end; c0 += 64) {
        int cnt = min(64, end - c0);
        f32x4 al4 = {-1e30f, -1e30f, -1e30f, -1e30f};
        int s = 0;
        if (lane < cnt) {
            s = srcs[c0 + lane];
            al4 = lky4(as4p[s] + adn4);
        }
        f32x4 mc = al4;
#pragma unroll
        for (int off = 32; off; off >>= 1) {
            mc.x = fmaxf(mc.x, __shfl_xor(mc.x, off));
            mc.y = fmaxf(mc.y, __shfl_xor(mc.y, off));
            mc.z = fmaxf(mc.z, __shfl_xor(mc.z, off));
            mc.w = fmaxf(mc.w, __shfl_xor(mc.w, off));
        }
        f32x4 mnew = max4(m4, mc);
        f32x4 sc4 = exp4(m4 - mnew);   // first chunk: exp(-inf)=0, acc already 0
        float sch = head == 0 ? sc4.x : head == 1 ? sc4.y : head == 2 ? sc4.z : sc4.w;
#pragma unroll
        for (int k = 0; k < 8; k++) acc[k] *= sch;
        denom *= sch;
        m4 = mnew;

        if (lane < cnt) {
            f32x4 ev = exp4(al4 - m4);
            s_lds[wv][lane] = s;
            e_lds[wv][0][lane] = ev.x;
            e_lds[wv][1][lane] = ev.y;
            e_lds[wv][2][lane] = ev.z;
            e_lds[wv][3][lane] = ev.w;
        }
        // 4 edges per half-wave in flight
        int j = half;
        for (; j + 6 < cnt; j += 8) {
            int s0 = s_lds[wv][j];
            int s1 = s_lds[wv][j + 2];
            int s2 = s_lds[wv][j + 4];
            int s3 = s_lds[wv][j + 6];
            float w0 = e_lds[wv][head][j];
            float w1 = e_lds[wv][head][j + 2];
            float w2 = e_lds[wv][head][j + 4];
            float w3 = e_lds[wv][head][j + 6];
            u16x8 g0 = *(const u16x8*)(Gb + (size_t)s0 * 256 + sl * 8);
            u16x8 g1 = *(const u16x8*)(Gb + (size_t)s1 * 256 + sl * 8);
            u16x8 g2 = *(const u16x8*)(Gb + (size_t)s2 * 256 + sl * 8);
            u16x8 g3 = *(const u16x8*)(Gb + (size_t)s3 * 256 + sl * 8);
            denom += (w0 + w1) + (w2 + w3);
#pragma unroll
            for (int k = 0; k < 8; k++) {
                acc[k] = fmaf(bf2f(g0[k]), w0, acc[k]);
                acc[k] = fmaf(bf2f(g1[k]), w1, acc[k]);
                acc[k] = fmaf(bf2f(g2[k]), w2, acc[k]);
                acc[k] = fmaf(bf2f(g3[k]), w3, acc[k]);
            }
        }
        for (; j < cnt; j += 2) {
            float wgt = e_lds[wv][head][j];
            int sj = s_lds[wv][j];
            u16x8 g8 = *(const u16x8*)(Gb + (size_t)sj * 256 + sl * 8);
            denom += wgt;
#pragma unroll
            for (int k = 0; k < 8; k++)
                acc[k] = fmaf(bf2f(g8[k]), wgt, acc[k]);
        }
    }

#pragma unroll
    for (int k = 0; k < 8; k++) acc[k] += __shfl_xor(acc[k], 32);
    denom += __shfl_xor(denom, 32);

    float rden = 1.0f / denom;
    float r[8];
    const float* bp = bias + sl * 8;
#pragma unroll
    for (int k = 0; k < 8; k++) r[k] = acc[k] * rden + bp[k];

    if (outF) {
        if (half == 0) {
            f32x4 v0 = {r[0], r[1], r[2], r[3]};
            f32x4 v1 = {r[4], r[5], r[6], r[7]};
            f32x4* op = (f32x4*)(outF + (size_t)n * 256 + sl * 8);
            op[0] = v0; op[1] = v1;
        }
    } else {
        if (half == 0) {
            u16x8 v;
#pragma unroll
            for (int k = 0; k < 8; k++) v[k] = f2bf_rne(fmaxf(r[k], 0.f));
            *(u16x8*)(outB + (size_t)n * 256 + sl * 8) = v;
        }
    }
}

// ---------------- launch ----------------

extern "C" void kernel_launch(void* const* d_in, const int* in_sizes, int n_in,
                              void* d_out, int out_size, void* d_ws, size_t ws_size,
                              hipStream_t stream) {
    const float* x   = (const float*)d_in[0];
    const int*   ei  = (const int*)d_in[1];
    const float* W1  = (const float*)d_in[2];
    const float* as1 = (const float*)d_in[3];
    const float* ad1 = (const float*)d_in[4];
    const float* b1  = (const float*)d_in[5];
    const float* W2  = (const float*)d_in[6];
    const float* as2 = (const float*)d_in[7];
    const float* ad2 = (const float*)d_in[8];
    const float* b2  = (const float*)d_in[9];

    int N = in_sizes[0] / 256;
    int E = in_sizes[1] / 2;
    int Etot = E + N;
    const int* srcE = ei;
    const int* dstE = ei + E;
    float* out = (float*)d_out;

    char* w = (char*)d_ws;
    size_t used = 0;
    auto alloc = [&](size_t bytes) -> char* {
        char* p = w + used;
        used += (bytes + 255) & ~(size_t)255;
        return p;
    };
    unsigned short* Gb = (unsigned short*)alloc((size_t)N * 256 * 2);  // GEMM output (bf16)
    unsigned short* Ab = (unsigned short*)alloc((size_t)N * 256 * 2);  // GEMM input (bf16)
    float* a_src   = (float*)alloc((size_t)N * 4 * 4);
    float* a_dst   = (float*)alloc((size_t)N * 4 * 4);
    int* counts    = (int*)alloc((size_t)N * 4);     // doubles as `fill` for scatter
    int* partial   = (int*)alloc((size_t)N * 4);
    int* row_ptr   = (int*)alloc(((size_t)N + 1) * 4);
    int* srcs      = (int*)alloc((size_t)Etot * 4);
    int* blockSums = (int*)alloc(256 * 4);
    unsigned short* Bt = (unsigned short*)alloc((size_t)256 * 512 * 2);

    hipMemsetAsync(counts, 0, (size_t)N * 4, stream);

    hist_kernel<<<(Etot + 255) / 256, 256, 0, stream>>>(dstE, counts, E, N);
    int nScanBlocks = (N + 1023) / 1024;
    scan1_kernel<<<nScanBlocks, 256, 0, stream>>>(counts, partial, blockSums, N);
    scan2_kernel<<<1, 64, 0, stream>>>(blockSums, nScanBlocks);
    finalize_kernel<<<(N + 255) / 256, 256, 0, stream>>>(partial, blockSums, row_ptr, N, Etot);
    hipMemsetAsync(counts, 0, (size_t)N * 4, stream);   // reuse as fill
    scatter_kernel<<<(Etot + 255) / 256, 256, 0, stream>>>(srcE, dstE, row_ptr, counts, srcs, E, N);

    int nodeBlocks = (N + 3) / 4;
    dim3 gg((N + 127) / 128, 2);

    // layer 1
    convertA_kernel<<<(N * 64 + 255) / 256, 256, 0, stream>>>(x, Ab, N);
    transposeW_kernel<<<256, 256, 0, stream>>>(W1, Bt);
    gemm_kernel<<<gg, 256, 0, stream>>>(Ab, Bt, Gb, N);
    attn_kernel<<<nodeBlocks, 256, 0, stream>>>(Gb, as1, ad1, a_src, a_dst, N);
    agg_kernel<<<nodeBlocks, 256, 0, stream>>>(Gb, a_src, a_dst, row_ptr, srcs, b1,
                                               nullptr, Ab, N);   // relu, bf16 -> layer-2 A

    // layer 2
    transposeW_kernel<<<256, 256, 0, stream>>>(W2, Bt);
    gemm_kernel<<<gg, 256, 0, stream>>>(Ab, Bt, Gb, N);
    attn_kernel<<<nodeBlocks, 256, 0, stream>>>(Gb, as2, ad2, a_src, a_dst, N);
    agg_kernel<<<nodeBlocks, 256, 0, stream>>>(Gb, a_src, a_dst, row_ptr, srcs, b2,
                                               out, nullptr, N);  // fp32 final
}

// Round 5
// 331.885 us; speedup vs baseline: 1.9108x; 1.0245x over previous
//
#include <hip/hip_runtime.h>
#include <math.h>

#define NEG_SLOPE 0.2f

typedef __attribute__((ext_vector_type(8))) short bf16x8;
typedef __attribute__((ext_vector_type(4))) float f32x4;
typedef __attribute__((ext_vector_type(4))) unsigned short u16x4;
typedef __attribute__((ext_vector_type(8))) unsigned short u16x8;

static __device__ __forceinline__ f32x4 lky4(f32x4 v) {
    f32x4 r;
    r.x = v.x >= 0.f ? v.x : NEG_SLOPE * v.x;
    r.y = v.y >= 0.f ? v.y : NEG_SLOPE * v.y;
    r.z = v.z >= 0.f ? v.z : NEG_SLOPE * v.z;
    r.w = v.w >= 0.f ? v.w : NEG_SLOPE * v.w;
    return r;
}
static __device__ __forceinline__ f32x4 max4(f32x4 a, f32x4 b) {
    f32x4 r;
    r.x = fmaxf(a.x, b.x); r.y = fmaxf(a.y, b.y);
    r.z = fmaxf(a.z, b.z); r.w = fmaxf(a.w, b.w);
    return r;
}
static __device__ __forceinline__ f32x4 exp4(f32x4 v) {
    f32x4 r;
    r.x = __expf(v.x); r.y = __expf(v.y); r.z = __expf(v.z); r.w = __expf(v.w);
    return r;
}
static __device__ __forceinline__ float bf2f(unsigned short u) {
    return __uint_as_float(((unsigned int)u) << 16);
}
static __device__ __forceinline__ unsigned short f2bf_rne(float f) {
    unsigned int u = __float_as_uint(f);
    u += 0x7fffu + ((u >> 16) & 1u);
    return (unsigned short)(u >> 16);
}

// ---------------- CSR build ----------------

__global__ void hist_kernel(const int* __restrict__ dst, int* __restrict__ counts, int E, int Nn) {
    int i = blockIdx.x * blockDim.x + threadIdx.x;
    int tot = E + Nn;
    if (i < tot) {
        int d = (i < E) ? dst[i] : (i - E);
        atomicAdd(&counts[d], 1);
    }
}

__global__ void scan1_kernel(const int* __restrict__ counts, int* __restrict__ partial,
                             int* __restrict__ blockSums, int Nn) {
    __shared__ int sh[1024];
    int b = blockIdx.x, t = threadIdx.x;
    int base = b * 1024;
    int orig[4];
    for (int r = 0; r < 4; r++) {
        int i = t + r * 256;
        int v = (base + i < Nn) ? counts[base + i] : 0;
        orig[r] = v;
        sh[i] = v;
    }
    __syncthreads();
    for (int off = 1; off < 1024; off <<= 1) {
        int vals[4];
        for (int r = 0; r < 4; r++) { int i = t + r * 256; vals[r] = (i >= off) ? sh[i - off] : 0; }
        __syncthreads();
        for (int r = 0; r < 4; r++) { int i = t + r * 256; sh[i] += vals[r]; }
        __syncthreads();
    }
    for (int r = 0; r < 4; r++) {
        int i = t + r * 256;
        if (base + i < Nn) partial[base + i] = sh[i] - orig[r];
    }
    if (t == 0) blockSums[b] = sh[1023];
}

__global__ void scan2_kernel(int* __restrict__ blockSums, int nb) {
    if (threadIdx.x == 0 && blockIdx.x == 0) {
        int s = 0;
        for (int i = 0; i < nb; i++) { int v = blockSums[i]; blockSums[i] = s; s += v; }
    }
}

__global__ void finalize_kernel(const int* __restrict__ partial, const int* __restrict__ blockOff,
                                int* __restrict__ row_ptr, int Nn, int Etot) {
    int i = blockIdx.x * blockDim.x + threadIdx.x;
    if (i < Nn) row_ptr[i] = partial[i] + blockOff[i >> 10];
    if (i == 0) row_ptr[Nn] = Etot;
}

__global__ void scatter_kernel(const int* __restrict__ srcE, const int* __restrict__ dstE,
                               const int* __restrict__ row_ptr, int* __restrict__ fill,
                               int* __restrict__ srcs, int E, int Nn) {
    int i = blockIdx.x * blockDim.x + threadIdx.x;
    int tot = E + Nn;
    if (i < tot) {
        int s, d;
        if (i < E) { s = srcE[i]; d = dstE[i]; }
        else       { s = d = i - E; }
        int pos = row_ptr[d] + atomicAdd(&fill[d], 1);
        srcs[pos] = s;
    }
}

// ---------------- fp32 -> bf16 RNE ----------------
__global__ void convertA_kernel(const float* __restrict__ X, unsigned short* __restrict__ Ab,
                                int rows) {
    int t = blockIdx.x * 256 + threadIdx.x;
    if (t >= rows * 64) return;
    int r = t >> 6, c4 = t & 63;
    f32x4 v = *((const f32x4*)(X + ((size_t)r << 8)) + c4);
    u16x4 o;
    o.x = f2bf_rne(v.x); o.y = f2bf_rne(v.y);
    o.z = f2bf_rne(v.z); o.w = f2bf_rne(v.w);
    *(u16x4*)(Ab + (size_t)r * 256 + c4 * 4) = o;
}

// W[k][n] fp32 -> Bt[n][k] = rne(w), Bt[n][256+k] = rne(w - hi)   (Bt: [256][512] bf16)
__global__ void transposeW_kernel(const float* __restrict__ W, unsigned short* __restrict__ Bt) {
    int t = blockIdx.x * 256 + threadIdx.x;   // 65536 threads
    int n = t >> 8, k = t & 255;
    float v = W[k * 256 + n];
    unsigned short hi = f2bf_rne(v);
    float hf = bf2f(hi);
    unsigned short lo = f2bf_rne(v - hf);
    Bt[(size_t)n * 512 + k] = hi;
    Bt[(size_t)n * 512 + 256 + k] = lo;
}

// ---------------- split-bf16 MFMA GEMM ----------------
// Gb[rows,256] (bf16 RNE) = Ab x (Wh + Wl) over K=512 bf16.
__global__ __launch_bounds__(256) void gemm_kernel(const unsigned short* __restrict__ Ab,
                                                   const unsigned short* __restrict__ Bt,
                                                   unsigned short* __restrict__ Gb,
                                                   int rows) {
    __shared__ __align__(128) unsigned char smem[32768];
    unsigned short* As = (unsigned short*)smem;            // [128][64] bf16
    unsigned short* Bs = (unsigned short*)(smem + 16384);  // [128][64]

    int tid = threadIdx.x;
    int lane = tid & 63, wid = tid >> 6;
    int wr = wid >> 1, wc = wid & 1;
    int bm = blockIdx.x * 128;
    int bn = blockIdx.y * 128;

    f32x4 zero4 = {0.f, 0.f, 0.f, 0.f};
    f32x4 acc[4][4];
#pragma unroll
    for (int i = 0; i < 4; i++)
#pragma unroll
        for (int j = 0; j < 4; j++) acc[i][j] = zero4;

    int sr = tid >> 3;   // 0..31
    int sc = tid & 7;    // chunk 0..7

    for (int kt = 0; kt < 512; kt += 64) {
        int kA = kt & 255;
#pragma unroll
        for (int q = 0; q < 4; q++) {
            int rt = q * 32 + sr;
            int gr = bm + rt; if (gr >= rows) gr = rows - 1;
            int cg = sc ^ (rt & 7);
            const unsigned short* gp = Ab + (size_t)gr * 256 + kA + cg * 8;
            unsigned short* lp = As + rt * 64 + sc * 8;
            __builtin_amdgcn_global_load_lds(
                (__attribute__((address_space(1))) void*)(uintptr_t)gp,
                (__attribute__((address_space(3))) void*)lp, 16, 0, 0);
        }
#pragma unroll
        for (int q = 0; q < 4; q++) {
            int rt = q * 32 + sr;
            int gn = bn + rt;
            int cg = sc ^ (rt & 7);
            const unsigned short* gp = Bt + (size_t)gn * 512 + kt + cg * 8;
            unsigned short* lp = Bs + rt * 64 + sc * 8;
            __builtin_amdgcn_global_load_lds(
                (__attribute__((address_space(1))) void*)(uintptr_t)gp,
                (__attribute__((address_space(3))) void*)lp, 16, 0, 0);
        }
        __syncthreads();
#pragma unroll
        for (int ks = 0; ks < 2; ks++) {
            bf16x8 af[4], bfr[4];
#pragma unroll
            for (int f = 0; f < 4; f++) {
                int r = wr * 64 + f * 16 + (lane & 15);
                int c = (ks * 4 + (lane >> 4)) ^ (r & 7);
                af[f] = *(const bf16x8*)(As + r * 64 + c * 8);
                int rb = wc * 64 + f * 16 + (lane & 15);
                int cb = (ks * 4 + (lane >> 4)) ^ (rb & 7);
                bfr[f] = *(const bf16x8*)(Bs + rb * 64 + cb * 8);
            }
#pragma unroll
            for (int i = 0; i < 4; i++)
#pragma unroll
                for (int j = 0; j < 4; j++)
                    acc[i][j] = __builtin_amdgcn_mfma_f32_16x16x32_bf16(af[i], bfr[j], acc[i][j], 0, 0, 0);
        }
        __syncthreads();
    }

    int r0 = wr * 64 + (lane >> 4) * 4;
    int c0 = wc * 64 + (lane & 15);
#pragma unroll
    for (int i = 0; i < 4; i++) {
#pragma unroll
        for (int j = 0; j < 4; j++) {
#pragma unroll
            for (int rg = 0; rg < 4; rg++) {
                int lr = bm + r0 + i * 16 + rg;
                if (lr < rows) {
                    int col = bn + c0 + j * 16;
                    Gb[(size_t)lr * 256 + col] = f2bf_rne(acc[i][j][rg]);
                }
            }
        }
    }
}

// ---------------- attention coefficients (wave per node, bf16 G) ----------------
__global__ __launch_bounds__(256) void attn_kernel(const unsigned short* __restrict__ Gb,
                                                   const float* __restrict__ att_s,
                                                   const float* __restrict__ att_d,
                                                   float* __restrict__ a_src,
                                                   float* __restrict__ a_dst, int N) {
    int wv = threadIdx.x >> 6, lane = threadIdx.x & 63;
    int n = blockIdx.x * 4 + wv;
    if (n >= N) return;
    u16x4 g4 = *(const u16x4*)(Gb + (size_t)n * 256 + lane * 4);
    f32x4 g;
    g.x = bf2f(g4.x); g.y = bf2f(g4.y); g.z = bf2f(g4.z); g.w = bf2f(g4.w);
    f32x4 s4 = ((const f32x4*)att_s)[lane];
    f32x4 d4 = ((const f32x4*)att_d)[lane];
    f32x4 p = g * s4, q = g * d4;
    float ps = p.x + p.y + p.z + p.w;
    float pd = q.x + q.y + q.z + q.w;
#pragma unroll
    for (int off = 1; off < 16; off <<= 1) {
        ps += __shfl_xor(ps, off);
        pd += __shfl_xor(pd, off);
    }
    if ((lane & 15) == 0) {
        int head = lane >> 4;
        a_src[n * 4 + head] = ps;
        a_dst[n * 4 + head] = pd;
    }
}

// ---------------- online-softmax aggregation ----------------
// Wave per node. Gathered rows are staged through a wave-private LDS ring via
// global_load_lds (2 edges / instr: lanes 0-31 row j, lanes 32-63 row j+1),
// double-buffered in groups of 4 edges with counted vmcnt (never drained to 0
// in steady state) -> deep MLP without VGPR pressure.
// outF != null -> fp32 (+bias), no relu (final layer)
// outB != null -> relu(h)+bias as bf16 RNE [256]/row (next layer's GEMM input)
__global__ __launch_bounds__(256) void agg_kernel(const unsigned short* __restrict__ Gb,
                                                  const float* __restrict__ a_src,
                                                  const float* __restrict__ a_dst,
                                                  const int* __restrict__ row_ptr,
                                                  const int* __restrict__ srcs,
                                                  const float* __restrict__ bias,
                                                  float* __restrict__ outF,
                                                  unsigned short* __restrict__ outB,
                                                  int N) {
    __shared__ float e_lds[4][4][68];
    __shared__ int s_lds[4][64];
    __shared__ __align__(128) unsigned short ring[4][8][256];   // [wave][edge slot][row]

    int wv = threadIdx.x >> 6, lane = threadIdx.x & 63;
    int n = blockIdx.x * 4 + wv;
    if (n >= N) return;
    int half = lane >> 5;   // 0/1
    int sl = lane & 31;     // 16B slice within the 512B row
    int head = sl >> 3;

    int start = row_ptr[n], end = row_ptr[n + 1];
    const f32x4* as4p = (const f32x4*)a_src;
    f32x4 adn4 = *(const f32x4*)(a_dst + (size_t)n * 4);

    s_lds[wv][lane] = n;   // safe garbage for never-consumed staged slots

    f32x4 m4 = {-1e30f, -1e30f, -1e30f, -1e30f};
    float acc[8] = {0.f, 0.f, 0.f, 0.f, 0.f, 0.f, 0.f, 0.f};
    float denom = 0.f;

    for (int c0 = start; c0 < end; c0 += 64) {
        int cnt = min(64, end - c0);
        f32x4 al4 = {-1e30f, -1e30f, -1e30f, -1e30f};
        int s = 0;
        if (lane < cnt) {
            s = srcs[c0 + lane];
            al4 = lky4(as4p[s] + adn4);
        }
        f32x4 mc = al4;
#pragma unroll
        for (int off = 32; off; off >>= 1) {
            mc.x = fmaxf(mc.x, __shfl_xor(mc.x, off));
            mc.y = fmaxf(mc.y, __shfl_xor(mc.y, off));
            mc.z = fmaxf(mc.z, __shfl_xor(mc.z, off));
            mc.w = fmaxf(mc.w, __shfl_xor(mc.w, off));
        }
        f32x4 mnew = max4(m4, mc);
        f32x4 sc4 = exp4(m4 - mnew);   // first chunk: exp(-inf)=0, acc already 0
        float sch = head == 0 ? sc4.x : head == 1 ? sc4.y : head == 2 ? sc4.z : sc4.w;
#pragma unroll
        for (int k = 0; k < 8; k++) acc[k] *= sch;
        denom *= sch;
        m4 = mnew;

        if (lane < cnt) {
            f32x4 ev = exp4(al4 - m4);
            s_lds[wv][lane] = s;
            e_lds[wv][0][lane] = ev.x;
            e_lds[wv][1][lane] = ev.y;
            e_lds[wv][2][lane] = ev.z;
            e_lds[wv][3][lane] = ev.w;
        }

        // ---- pipelined gather: groups of 4 edges, 2 LDS buffers ----
        int ng = (cnt + 3) >> 2;

        auto stage = [&](int g) {
            int buf = g & 1;
#pragma unroll
            for (int i = 0; i < 2; i++) {
                int e = g * 4 + i * 2 + half;          // this lane's edge slot
                int sj = s_lds[wv][e];                 // valid (possibly garbage) node id
                const unsigned short* gp = Gb + (size_t)sj * 256 + sl * 8;
                unsigned short* lp = &ring[wv][buf * 4 + i * 2][0];  // wave-uniform
                __builtin_amdgcn_global_load_lds(
                    (__attribute__((address_space(1))) void*)(uintptr_t)gp,
                    (__attribute__((address_space(3))) void*)lp, 16, 0, 0);
            }
        };

        stage(0);
        for (int g = 0; g < ng; g++) {
            if (g + 1 < ng) {
                stage(g + 1);
                asm volatile("s_waitcnt vmcnt(2)" ::: "memory");
            } else {
                asm volatile("s_waitcnt vmcnt(0)" ::: "memory");
            }
            int cg = cnt - g * 4; if (cg > 4) cg = 4;
            const unsigned short* bufp = &ring[wv][(g & 1) * 4][0];
#pragma unroll
            for (int t = 0; t < 2; t++) {
                int e = half * 2 + t;                  // half 0: edges 0,1; half 1: edges 2,3
                if (e < cg) {
                    float wgt = e_lds[wv][head][g * 4 + e];
                    u16x8 g8 = *(const u16x8*)(bufp + e * 256 + sl * 8);
                    denom += wgt;
#pragma unroll
                    for (int k = 0; k < 8; k++)
                        acc[k] = fmaf(bf2f(g8[k]), wgt, acc[k]);
                }
            }
        }
    }

#pragma unroll
    for (int k = 0; k < 8; k++) acc[k] += __shfl_xor(acc[k], 32);
    denom += __shfl_xor(denom, 32);

    float rden = 1.0f / denom;
    float r[8];
    const float* bp = bias + sl * 8;
#pragma unroll
    for (int k = 0; k < 8; k++) r[k] = acc[k] * rden + bp[k];

    if (outF) {
        if (half == 0) {
            f32x4 v0 = {r[0], r[1], r[2], r[3]};
            f32x4 v1 = {r[4], r[5], r[6], r[7]};
            f32x4* op = (f32x4*)(outF + (size_t)n * 256 + sl * 8);
            op[0] = v0; op[1] = v1;
        }
    } else {
        if (half == 0) {
            u16x8 v;
#pragma unroll
            for (int k = 0; k < 8; k++) v[k] = f2bf_rne(fmaxf(r[k], 0.f));
            *(u16x8*)(outB + (size_t)n * 256 + sl * 8) = v;
        }
    }
}

// ---------------- launch ----------------

extern "C" void kernel_launch(void* const* d_in, const int* in_sizes, int n_in,
                              void* d_out, int out_size, void* d_ws, size_t ws_size,
                              hipStream_t stream) {
    const float* x   = (const float*)d_in[0];
    const int*   ei  = (const int*)d_in[1];
    const float* W1  = (const float*)d_in[2];
    const float* as1 = (const float*)d_in[3];
    const float* ad1 = (const float*)d_in[4];
    const float* b1  = (const float*)d_in[5];
    const float* W2  = (const float*)d_in[6];
    const float* as2 = (const float*)d_in[7];
    const float* ad2 = (const float*)d_in[8];
    const float* b2  = (const float*)d_in[9];

    int N = in_sizes[0] / 256;
    int E = in_sizes[1] / 2;
    int Etot = E + N;
    const int* srcE = ei;
    const int* dstE = ei + E;
    float* out = (float*)d_out;

    char* w = (char*)d_ws;
    size_t used = 0;
    auto alloc = [&](size_t bytes) -> char* {
        char* p = w + used;
        used += (bytes + 255) & ~(size_t)255;
        return p;
    };
    unsigned short* Gb = (unsigned short*)alloc((size_t)N * 256 * 2);  // GEMM output (bf16)
    unsigned short* Ab = (unsigned short*)alloc((size_t)N * 256 * 2);  // GEMM input (bf16)
    float* a_src   = (float*)alloc((size_t)N * 4 * 4);
    float* a_dst   = (float*)alloc((size_t)N * 4 * 4);
    int* counts    = (int*)alloc((size_t)N * 4);     // doubles as `fill` for scatter
    int* partial   = (int*)alloc((size_t)N * 4);
    int* row_ptr   = (int*)alloc(((size_t)N + 1) * 4);
    int* srcs      = (int*)alloc((size_t)Etot * 4);
    int* blockSums = (int*)alloc(256 * 4);
    unsigned short* Bt = (unsigned short*)alloc((size_t)256 * 512 * 2);

    hipMemsetAsync(counts, 0, (size_t)N * 4, stream);

    hist_kernel<<<(Etot + 255) / 256, 256, 0, stream>>>(dstE, counts, E, N);
    int nScanBlocks = (N + 1023) / 1024;
    scan1_kernel<<<nScanBlocks, 256, 0, stream>>>(counts, partial, blockSums, N);
    scan2_kernel<<<1, 64, 0, stream>>>(blockSums, nScanBlocks);
    finalize_kernel<<<(N + 255) / 256, 256, 0, stream>>>(partial, blockSums, row_ptr, N, Etot);
    hipMemsetAsync(counts, 0, (size_t)N * 4, stream);   // reuse as fill
    scatter_kernel<<<(Etot + 255) / 256, 256, 0, stream>>>(srcE, dstE, row_ptr, counts, srcs, E, N);

    int nodeBlocks = (N + 3) / 4;
    dim3 gg((N + 127) / 128, 2);

    // layer 1
    convertA_kernel<<<(N * 64 + 255) / 256, 256, 0, stream>>>(x, Ab, N);
    transposeW_kernel<<<256, 256, 0, stream>>>(W1, Bt);
    gemm_kernel<<<gg, 256, 0, stream>>>(Ab, Bt, Gb, N);
    attn_kernel<<<nodeBlocks, 256, 0, stream>>>(Gb, as1, ad1, a_src, a_dst, N);
    agg_kernel<<<nodeBlocks, 256, 0, stream>>>(Gb, a_src, a_dst, row_ptr, srcs, b1,
                                               nullptr, Ab, N);   // relu, bf16 -> layer-2 A

    // layer 2
    transposeW_kernel<<<256, 256, 0, stream>>>(W2, Bt);
    gemm_kernel<<<gg, 256, 0, stream>>>(Ab, Bt, Gb, N);
    attn_kernel<<<nodeBlocks, 256, 0, stream>>>(Gb, as2, ad2, a_src, a_dst, N);
    agg_kernel<<<nodeBlocks, 256, 0, stream>>>(Gb, a_src, a_dst, row_ptr, srcs, b2,
                                               out, nullptr, N);  // fp32 final
}

// Round 6
// 326.452 us; speedup vs baseline: 1.9426x; 1.0166x over previous
//
#include <hip/hip_runtime.h>
#include <math.h>

#define NEG_SLOPE 0.2f

typedef __attribute__((ext_vector_type(8))) short bf16x8;
typedef __attribute__((ext_vector_type(4))) float f32x4;
typedef __attribute__((ext_vector_type(4))) unsigned short u16x4;
typedef __attribute__((ext_vector_type(8))) unsigned short u16x8;

static __device__ __forceinline__ f32x4 lky4(f32x4 v) {
    f32x4 r;
    r.x = v.x >= 0.f ? v.x : NEG_SLOPE * v.x;
    r.y = v.y >= 0.f ? v.y : NEG_SLOPE * v.y;
    r.z = v.z >= 0.f ? v.z : NEG_SLOPE * v.z;
    r.w = v.w >= 0.f ? v.w : NEG_SLOPE * v.w;
    return r;
}
static __device__ __forceinline__ f32x4 exp4(f32x4 v) {
    f32x4 r;
    r.x = __expf(v.x); r.y = __expf(v.y); r.z = __expf(v.z); r.w = __expf(v.w);
    return r;
}
static __device__ __forceinline__ float bf2f(unsigned short u) {
    return __uint_as_float(((unsigned int)u) << 16);
}
static __device__ __forceinline__ unsigned short f2bf_rne(float f) {
    unsigned int u = __float_as_uint(f);
    u += 0x7fffu + ((u >> 16) & 1u);
    return (unsigned short)(u >> 16);
}

// ---------------- CSR build ----------------

__global__ void hist_kernel(const int* __restrict__ dst, int* __restrict__ counts, int E, int Nn) {
    int i = blockIdx.x * blockDim.x + threadIdx.x;
    int tot = E + Nn;
    if (i < tot) {
        int d = (i < E) ? dst[i] : (i - E);
        atomicAdd(&counts[d], 1);
    }
}

__global__ void scan1_kernel(const int* __restrict__ counts, int* __restrict__ partial,
                             int* __restrict__ blockSums, int Nn) {
    __shared__ int sh[1024];
    int b = blockIdx.x, t = threadIdx.x;
    int base = b * 1024;
    int orig[4];
    for (int r = 0; r < 4; r++) {
        int i = t + r * 256;
        int v = (base + i < Nn) ? counts[base + i] : 0;
        orig[r] = v;
        sh[i] = v;
    }
    __syncthreads();
    for (int off = 1; off < 1024; off <<= 1) {
        int vals[4];
        for (int r = 0; r < 4; r++) { int i = t + r * 256; vals[r] = (i >= off) ? sh[i - off] : 0; }
        __syncthreads();
        for (int r = 0; r < 4; r++) { int i = t + r * 256; sh[i] += vals[r]; }
        __syncthreads();
    }
    for (int r = 0; r < 4; r++) {
        int i = t + r * 256;
        if (base + i < Nn) partial[base + i] = sh[i] - orig[r];
    }
    if (t == 0) blockSums[b] = sh[1023];
}

__global__ void scan2_kernel(int* __restrict__ blockSums, int nb) {
    if (threadIdx.x == 0 && blockIdx.x == 0) {
        int s = 0;
        for (int i = 0; i < nb; i++) { int v = blockSums[i]; blockSums[i] = s; s += v; }
    }
}

__global__ void finalize_kernel(const int* __restrict__ partial, const int* __restrict__ blockOff,
                                int* __restrict__ row_ptr, int Nn, int Etot) {
    int i = blockIdx.x * blockDim.x + threadIdx.x;
    if (i < Nn) row_ptr[i] = partial[i] + blockOff[i >> 10];
    if (i == 0) row_ptr[Nn] = Etot;
}

__global__ void scatter_kernel(const int* __restrict__ srcE, const int* __restrict__ dstE,
                               const int* __restrict__ row_ptr, int* __restrict__ fill,
                               int* __restrict__ srcs, int E, int Nn) {
    int i = blockIdx.x * blockDim.x + threadIdx.x;
    int tot = E + Nn;
    if (i < tot) {
        int s, d;
        if (i < E) { s = srcE[i]; d = dstE[i]; }
        else       { s = d = i - E; }
        int pos = row_ptr[d] + atomicAdd(&fill[d], 1);
        srcs[pos] = s;
    }
}

// ---------------- fp32 -> bf16 RNE ----------------
__global__ void convertA_kernel(const float* __restrict__ X, unsigned short* __restrict__ Ab,
                                int rows) {
    int t = blockIdx.x * 256 + threadIdx.x;
    if (t >= rows * 64) return;
    int r = t >> 6, c4 = t & 63;
    f32x4 v = *((const f32x4*)(X + ((size_t)r << 8)) + c4);
    u16x4 o;
    o.x = f2bf_rne(v.x); o.y = f2bf_rne(v.y);
    o.z = f2bf_rne(v.z); o.w = f2bf_rne(v.w);
    *(u16x4*)(Ab + (size_t)r * 256 + c4 * 4) = o;
}

// W[k][n] fp32 -> Bt[n][k] bf16 RNE  (Bt: [256][256])
__global__ void transposeW_kernel(const float* __restrict__ W, unsigned short* __restrict__ Bt) {
    int t = blockIdx.x * 256 + threadIdx.x;   // 65536 threads
    int n = t >> 8, k = t & 255;
    Bt[(size_t)n * 256 + k] = f2bf_rne(W[k * 256 + n]);
}

// ---------------- bf16 MFMA GEMM, K=256, 2-phase double-buffered ----------------
// Gb[rows,256] (bf16 RNE) = Ab x Bt^T.
__global__ __launch_bounds__(256) void gemm_kernel(const unsigned short* __restrict__ Ab,
                                                   const unsigned short* __restrict__ Bt,
                                                   unsigned short* __restrict__ Gb,
                                                   int rows) {
    __shared__ __align__(128) unsigned char smem[65536];   // 2 x (As 16KB + Bs 16KB)

    int tid = threadIdx.x;
    int lane = tid & 63, wid = tid >> 6;
    int wr = wid >> 1, wc = wid & 1;
    int bm = blockIdx.x * 128;
    int bn = blockIdx.y * 128;

    f32x4 zero4 = {0.f, 0.f, 0.f, 0.f};
    f32x4 acc[4][4];
#pragma unroll
    for (int i = 0; i < 4; i++)
#pragma unroll
        for (int j = 0; j < 4; j++) acc[i][j] = zero4;

    int sr = tid >> 3;   // 0..31
    int sc = tid & 7;    // chunk 0..7

    auto stage = [&](int kt, int buf) {
        unsigned short* As = (unsigned short*)(smem + buf * 32768);
        unsigned short* Bs = As + 8192;
#pragma unroll
        for (int q = 0; q < 4; q++) {
            int rt = q * 32 + sr;
            int gr = bm + rt; if (gr >= rows) gr = rows - 1;
            int cg = sc ^ (rt & 7);
            const unsigned short* gp = Ab + (size_t)gr * 256 + kt + cg * 8;
            unsigned short* lp = As + rt * 64 + sc * 8;
            __builtin_amdgcn_global_load_lds(
                (__attribute__((address_space(1))) void*)(uintptr_t)gp,
                (__attribute__((address_space(3))) void*)lp, 16, 0, 0);
        }
#pragma unroll
        for (int q = 0; q < 4; q++) {
            int rt = q * 32 + sr;
            int gn = bn + rt;
            int cg = sc ^ (rt & 7);
            const unsigned short* gp = Bt + (size_t)gn * 256 + kt + cg * 8;
            unsigned short* lp = Bs + rt * 64 + sc * 8;
            __builtin_amdgcn_global_load_lds(
                (__attribute__((address_space(1))) void*)(uintptr_t)gp,
                (__attribute__((address_space(3))) void*)lp, 16, 0, 0);
        }
    };

    stage(0, 0);
    __syncthreads();   // compiler drains vmcnt before barrier

    for (int kt = 0; kt < 4; kt++) {
        if (kt < 3) stage((kt + 1) * 64, (kt + 1) & 1);   // overlap next stage with compute
        unsigned short* As = (unsigned short*)(smem + (kt & 1) * 32768);
        unsigned short* Bs = As + 8192;
#pragma unroll
        for (int ks = 0; ks < 2; ks++) {
            bf16x8 af[4], bfr[4];
#pragma unroll
            for (int f = 0; f < 4; f++) {
                int r = wr * 64 + f * 16 + (lane & 15);
                int c = (ks * 4 + (lane >> 4)) ^ (r & 7);
                af[f] = *(const bf16x8*)(As + r * 64 + c * 8);
                int rb = wc * 64 + f * 16 + (lane & 15);
                int cb = (ks * 4 + (lane >> 4)) ^ (rb & 7);
                bfr[f] = *(const bf16x8*)(Bs + rb * 64 + cb * 8);
            }
#pragma unroll
            for (int i = 0; i < 4; i++)
#pragma unroll
                for (int j = 0; j < 4; j++)
                    acc[i][j] = __builtin_amdgcn_mfma_f32_16x16x32_bf16(af[i], bfr[j], acc[i][j], 0, 0, 0);
        }
        __syncthreads();   // drains the in-flight stage; next buffer ready
    }

    int r0 = wr * 64 + (lane >> 4) * 4;
    int c0 = wc * 64 + (lane & 15);
#pragma unroll
    for (int i = 0; i < 4; i++) {
#pragma unroll
        for (int j = 0; j < 4; j++) {
#pragma unroll
            for (int rg = 0; rg < 4; rg++) {
                int lr = bm + r0 + i * 16 + rg;
                if (lr < rows) {
                    int col = bn + c0 + j * 16;
                    Gb[(size_t)lr * 256 + col] = f2bf_rne(acc[i][j][rg]);
                }
            }
        }
    }
}

// ---------------- attention coefficients (wave per node, bf16 G) ----------------
__global__ __launch_bounds__(256) void attn_kernel(const unsigned short* __restrict__ Gb,
                                                   const float* __restrict__ att_s,
                                                   const float* __restrict__ att_d,
                                                   float* __restrict__ a_src,
                                                   float* __restrict__ a_dst, int N) {
    int wv = threadIdx.x >> 6, lane = threadIdx.x & 63;
    int n = blockIdx.x * 4 + wv;
    if (n >= N) return;
    u16x4 g4 = *(const u16x4*)(Gb + (size_t)n * 256 + lane * 4);
    f32x4 g;
    g.x = bf2f(g4.x); g.y = bf2f(g4.y); g.z = bf2f(g4.z); g.w = bf2f(g4.w);
    f32x4 s4 = ((const f32x4*)att_s)[lane];
    f32x4 d4 = ((const f32x4*)att_d)[lane];
    f32x4 p = g * s4, q = g * d4;
    float ps = p.x + p.y + p.z + p.w;
    float pd = q.x + q.y + q.z + q.w;
#pragma unroll
    for (int off = 1; off < 16; off <<= 1) {
        ps += __shfl_xor(ps, off);
        pd += __shfl_xor(pd, off);
    }
    if ((lane & 15) == 0) {
        int head = lane >> 4;
        a_src[n * 4 + head] = ps;
        a_dst[n * 4 + head] = pd;
    }
}

// ---------------- normalized edge weights (wave per node) ----------------
// No max-subtraction: alphas are O(10), exp() is safe in fp32, and softmax is
// shift-invariant so the result matches the reference to fp rounding.
// wts[e][h] = exp(alpha_eh) / sum_row exp(alpha_h)
__global__ __launch_bounds__(256) void wts_kernel(const float* __restrict__ a_src,
                                                  const float* __restrict__ a_dst,
                                                  const int* __restrict__ row_ptr,
                                                  const int* __restrict__ srcs,
                                                  float* __restrict__ wts, int N) {
    int wv = threadIdx.x >> 6, lane = threadIdx.x & 63;
    int n = blockIdx.x * 4 + wv;
    if (n >= N) return;
    int start = row_ptr[n], end = row_ptr[n + 1];
    const f32x4* as4p = (const f32x4*)a_src;
    f32x4 adn4 = *(const f32x4*)(a_dst + (size_t)n * 4);

    f32x4 zero = {0.f, 0.f, 0.f, 0.f};
    f32x4 ev0 = zero;
    int e0 = start + lane;
    if (e0 < end) {
        int s = srcs[e0];
        ev0 = exp4(lky4(as4p[s] + adn4));
    }
    f32x4 denom4 = ev0;
    for (int c0 = start + 64; c0 < end; c0 += 64) {   // rare (>64-degree nodes)
        int e = c0 + lane;
        if (e < end) {
            int s = srcs[e];
            denom4 += exp4(lky4(as4p[s] + adn4));
        }
    }
#pragma unroll
    for (int off = 32; off; off >>= 1) {
        denom4.x += __shfl_xor(denom4.x, off);
        denom4.y += __shfl_xor(denom4.y, off);
        denom4.z += __shfl_xor(denom4.z, off);
        denom4.w += __shfl_xor(denom4.w, off);
    }
    f32x4 rd;
    rd.x = 1.0f / denom4.x; rd.y = 1.0f / denom4.y;
    rd.z = 1.0f / denom4.z; rd.w = 1.0f / denom4.w;

    if (e0 < end) ((f32x4*)wts)[e0] = ev0 * rd;
    for (int c0 = start + 64; c0 < end; c0 += 64) {
        int e = c0 + lane;
        if (e < end) {
            int s = srcs[e];
            ((f32x4*)wts)[e] = exp4(lky4(as4p[s] + adn4)) * rd;
        }
    }
}

// ---------------- weighted gather (wave per node, no LDS, no softmax) ----------------
// outF != null -> fp32 (+bias), no relu (final layer)
// outB != null -> relu(h)+bias as bf16 RNE (next layer's GEMM input)
__global__ __launch_bounds__(256) void gather_kernel(const unsigned short* __restrict__ Gb,
                                                     const float* __restrict__ wts,
                                                     const int* __restrict__ row_ptr,
                                                     const int* __restrict__ srcs,
                                                     const float* __restrict__ bias,
                                                     float* __restrict__ outF,
                                                     unsigned short* __restrict__ outB,
                                                     int N) {
    int wv = threadIdx.x >> 6, lane = threadIdx.x & 63;
    int n = blockIdx.x * 4 + wv;
    if (n >= N) return;
    int half = lane >> 5;   // which edge of a pair
    int sl = lane & 31;     // 16B slice of the 512B row
    int head = sl >> 3;

    int start = row_ptr[n], end = row_ptr[n + 1];

    float acc[8] = {0.f, 0.f, 0.f, 0.f, 0.f, 0.f, 0.f, 0.f};

    int e = start + half;
    // 2-deep unroll: 4 rows in flight per wave
    for (; e + 2 < end; e += 4) {
        int s0 = srcs[e];
        int s1 = srcs[e + 2];
        float w0 = wts[e * 4 + head];
        float w1 = wts[(e + 2) * 4 + head];
        u16x8 g0 = *(const u16x8*)(Gb + (size_t)s0 * 256 + sl * 8);
        u16x8 g1 = *(const u16x8*)(Gb + (size_t)s1 * 256 + sl * 8);
#pragma unroll
        for (int k = 0; k < 8; k++) {
            acc[k] = fmaf(bf2f(g0[k]), w0, acc[k]);
            acc[k] = fmaf(bf2f(g1[k]), w1, acc[k]);
        }
    }
    for (; e < end; e += 2) {
        int s0 = srcs[e];
        float w0 = wts[e * 4 + head];
        u16x8 g0 = *(const u16x8*)(Gb + (size_t)s0 * 256 + sl * 8);
#pragma unroll
        for (int k = 0; k < 8; k++)
            acc[k] = fmaf(bf2f(g0[k]), w0, acc[k]);
    }

#pragma unroll
    for (int k = 0; k < 8; k++) acc[k] += __shfl_xor(acc[k], 32);

    float r[8];
    const float* bp = bias + sl * 8;
#pragma unroll
    for (int k = 0; k < 8; k++) r[k] = acc[k] + bp[k];

    if (outF) {
        if (half == 0) {
            f32x4 v0 = {r[0], r[1], r[2], r[3]};
            f32x4 v1 = {r[4], r[5], r[6], r[7]};
            f32x4* op = (f32x4*)(outF + (size_t)n * 256 + sl * 8);
            op[0] = v0; op[1] = v1;
        }
    } else {
        if (half == 0) {
            u16x8 v;
#pragma unroll
            for (int k = 0; k < 8; k++) v[k] = f2bf_rne(fmaxf(r[k], 0.f));
            *(u16x8*)(outB + (size_t)n * 256 + sl * 8) = v;
        }
    }
}

// ---------------- launch ----------------

extern "C" void kernel_launch(void* const* d_in, const int* in_sizes, int n_in,
                              void* d_out, int out_size, void* d_ws, size_t ws_size,
                              hipStream_t stream) {
    const float* x   = (const float*)d_in[0];
    const int*   ei  = (const int*)d_in[1];
    const float* W1  = (const float*)d_in[2];
    const float* as1 = (const float*)d_in[3];
    const float* ad1 = (const float*)d_in[4];
    const float* b1  = (const float*)d_in[5];
    const float* W2  = (const float*)d_in[6];
    const float* as2 = (const float*)d_in[7];
    const float* ad2 = (const float*)d_in[8];
    const float* b2  = (const float*)d_in[9];

    int N = in_sizes[0] / 256;
    int E = in_sizes[1] / 2;
    int Etot = E + N;
    const int* srcE = ei;
    const int* dstE = ei + E;
    float* out = (float*)d_out;

    char* w = (char*)d_ws;
    size_t used = 0;
    auto alloc = [&](size_t bytes) -> char* {
        char* p = w + used;
        used += (bytes + 255) & ~(size_t)255;
        return p;
    };
    unsigned short* Gb = (unsigned short*)alloc((size_t)N * 256 * 2);  // GEMM output (bf16)
    unsigned short* Ab = (unsigned short*)alloc((size_t)N * 256 * 2);  // GEMM input (bf16)
    float* a_src   = (float*)alloc((size_t)N * 4 * 4);
    float* a_dst   = (float*)alloc((size_t)N * 4 * 4);
    float* wts     = (float*)alloc((size_t)Etot * 4 * 4);              // normalized weights
    int* counts    = (int*)alloc((size_t)N * 4);     // doubles as `fill` for scatter
    int* partial   = (int*)alloc((size_t)N * 4);
    int* row_ptr   = (int*)alloc(((size_t)N + 1) * 4);
    int* srcs      = (int*)alloc((size_t)Etot * 4);
    int* blockSums = (int*)alloc(256 * 4);
    unsigned short* Bt = (unsigned short*)alloc((size_t)256 * 256 * 2);

    hipMemsetAsync(counts, 0, (size_t)N * 4, stream);

    hist_kernel<<<(Etot + 255) / 256, 256, 0, stream>>>(dstE, counts, E, N);
    int nScanBlocks = (N + 1023) / 1024;
    scan1_kernel<<<nScanBlocks, 256, 0, stream>>>(counts, partial, blockSums, N);
    scan2_kernel<<<1, 64, 0, stream>>>(blockSums, nScanBlocks);
    finalize_kernel<<<(N + 255) / 256, 256, 0, stream>>>(partial, blockSums, row_ptr, N, Etot);
    hipMemsetAsync(counts, 0, (size_t)N * 4, stream);   // reuse as fill
    scatter_kernel<<<(Etot + 255) / 256, 256, 0, stream>>>(srcE, dstE, row_ptr, counts, srcs, E, N);

    int nodeBlocks = (N + 3) / 4;
    dim3 gg((N + 127) / 128, 2);

    // layer 1
    convertA_kernel<<<(N * 64 + 255) / 256, 256, 0, stream>>>(x, Ab, N);
    transposeW_kernel<<<256, 256, 0, stream>>>(W1, Bt);
    gemm_kernel<<<gg, 256, 0, stream>>>(Ab, Bt, Gb, N);
    attn_kernel<<<nodeBlocks, 256, 0, stream>>>(Gb, as1, ad1, a_src, a_dst, N);
    wts_kernel<<<nodeBlocks, 256, 0, stream>>>(a_src, a_dst, row_ptr, srcs, wts, N);
    gather_kernel<<<nodeBlocks, 256, 0, stream>>>(Gb, wts, row_ptr, srcs, b1,
                                                  nullptr, Ab, N);   // relu+bf16 -> layer-2 A

    // layer 2
    transposeW_kernel<<<256, 256, 0, stream>>>(W2, Bt);
    gemm_kernel<<<gg, 256, 0, stream>>>(Ab, Bt, Gb, N);
    attn_kernel<<<nodeBlocks, 256, 0, stream>>>(Gb, as2, ad2, a_src, a_dst, N);
    wts_kernel<<<nodeBlocks, 256, 0, stream>>>(a_src, a_dst, row_ptr, srcs, wts, N);
    gather_kernel<<<nodeBlocks, 256, 0, stream>>>(Gb, wts, row_ptr, srcs, b2,
                                                  out, nullptr, N);  // fp32 final
}